// Round 14
// baseline (740.247 us; speedup 1.0000x reference)
//
#include <hip/hip_runtime.h>
#include <hip/hip_bf16.h>
#include <stdint.h>

typedef unsigned short u16;
typedef unsigned int u32;
typedef unsigned long long u64;
typedef __attribute__((ext_vector_type(8))) short short8;
typedef __attribute__((ext_vector_type(4))) float f32x4;
typedef __attribute__((ext_vector_type(2))) unsigned int u32x2;
typedef __attribute__((ext_vector_type(4))) unsigned int u32x4;

#define BB 4
#define TT 1024
#define CC 2048

// ---------- helpers ----------
__device__ __forceinline__ u16 f2bf(float f){
  __hip_bfloat16 h = __float2bfloat16(f);
  return *reinterpret_cast<u16*>(&h);
}
__device__ __forceinline__ float bf2f(u16 h){
  union { u32 u; float f; } v; v.u = ((u32)h) << 16; return v.f;
}
__device__ __forceinline__ float bflo(u32 p){
  union { u32 u; float f; } v; v.u = p << 16; return v.f;
}
__device__ __forceinline__ float bfhi(u32 p){
  union { u32 u; float f; } v; v.u = p & 0xFFFF0000u; return v.f;
}

__device__ __forceinline__ void gload16(const void* g, void* s){
  __builtin_amdgcn_global_load_lds((const __attribute__((address_space(1))) u32*)g,
                                   (__attribute__((address_space(3))) u32*)s, 16, 0, 0);
}

__device__ __forceinline__ float wave_sum64(float x){
  #pragma unroll
  for (int m = 1; m < 64; m <<= 1) x += __shfl_xor(x, m, 64);
  return x;
}

template<int N>
__device__ __forceinline__ float ror_add(float x){
  int t = __builtin_amdgcn_update_dpp(0, __builtin_bit_cast(int, x), 0x120 | N, 0xF, 0xF, false);
  return x + __builtin_bit_cast(float, t);
}
__device__ __forceinline__ float red16(float x){
  x = ror_add<8>(x); x = ror_add<4>(x); x = ror_add<2>(x); x = ror_add<1>(x);
  return x;
}

// SRSRC buffer descriptor: base ptr + byte size (stride=0 raw buffer)
__device__ __forceinline__ u32x4 make_srsrc(const void* p, u32 bytes){
  union { const void* p; u32 w[2]; } a; a.p = p;
  u32x4 d; d.x = a.w[0]; d.y = a.w[1] & 0xFFFFu; d.z = bytes; d.w = 0x00020000u;
  return d;
}

// Bijective XCD-chunked swizzle (m204), bx-major within an A-row-panel.
__device__ __forceinline__ void xcd_map(int nx, int& bx, int& row0){
  const int G = gridDim.x;
  const int q = G >> 3, r = G & 7;
  const int xcd = blockIdx.x & 7, i2 = blockIdx.x >> 3;
  const int sw = (xcd < r) ? (xcd*(q+1) + i2) : (r*(q+1) + (xcd - r)*q + i2);
  const int by = sw / nx;
  bx = sw - by*nx;
  row0 = by * 128;
}

// ---------- fused weight casts ----------
__global__ __launch_bounds__(256) void k_cast4(
  const float* __restrict__ wr, const float* __restrict__ wk,
  const float* __restrict__ wv, const float* __restrict__ wo,
  u16* __restrict__ wsb)
{
  int i = blockIdx.x*256 + threadIdx.x;
  int seg = i >> 20;
  int off = (i & 1048575) * 4;
  const float* src = (seg==0) ? wr : (seg==1) ? wk : (seg==2) ? wv : wo;
  const size_t dofs = (seg==0) ? 4194304u : (seg==1) ? 8388608u : (seg==2) ? 12582912u : 0u;
  float4 v = *(const float4*)&src[off];
  *(ushort4*)&wsb[dofs + off] = make_ushort4(f2bf(v.x), f2bf(v.y), f2bf(v.z), f2bf(v.w));
}

// ---------- fused tiled transposes ----------
__global__ __launch_bounds__(256) void k_tpadA(
  const float* __restrict__ w1, const float* __restrict__ a1,
  const float* __restrict__ v1, const float* __restrict__ g1,
  const float* __restrict__ w2, const float* __restrict__ a2,
  const float* __restrict__ v2, const float* __restrict__ g2,
  u16* __restrict__ wsb)
{
  __shared__ float lds[32][33];
  const int blk = blockIdx.x;
  const float* src; int R, S, Rpad, tile, tiles_r; size_t dst;
  if      (blk <  256){ src=w1; R=2048; S=96;   Rpad=2048; dst=16777216u; tile=blk;      tiles_r=64; }
  else if (blk <  512){ src=a1; R=2048; S=96;   Rpad=2048; dst=17039360u; tile=blk-256;  tiles_r=64; }
  else if (blk <  768){ src=v1; R=2048; S=64;   Rpad=2048; dst=17301504u; tile=blk-512;  tiles_r=64; }
  else if (blk < 1280){ src=g1; R=2048; S=256;  Rpad=2048; dst=17563648u; tile=blk-768;  tiles_r=64; }
  else if (blk < 1536){ src=w2; R=96;   S=2048; Rpad=128;  dst=18087936u; tile=blk-1280; tiles_r=4;  }
  else if (blk < 1792){ src=a2; R=96;   S=2048; Rpad=128;  dst=18350080u; tile=blk-1536; tiles_r=4;  }
  else if (blk < 2048){ src=v2; R=64;   S=2048; Rpad=128;  dst=18612224u; tile=blk-1792; tiles_r=4;  }
  else                { src=g2; R=256;  S=2048; Rpad=256;  dst=18874368u; tile=blk-2048; tiles_r=8;  }
  const int tr = tile % tiles_r, ts = tile / tiles_r;
  const int r0 = tr*32, s0 = ts*32;
  const int tj = threadIdx.x & 31, ti = threadIdx.x >> 5;
  #pragma unroll
  for (int p=0;p<4;p++){
    int rr = r0 + p*8 + ti, ss = s0 + tj;
    lds[p*8+ti][tj] = (rr < R && ss < S) ? src[(size_t)rr*S + ss] : 0.f;
  }
  __syncthreads();
  #pragma unroll
  for (int p=0;p<4;p++){
    int sl = p*8 + ti, rl = tj;
    wsb[dst + (size_t)(s0+sl)*Rpad + r0 + rl] = f2bf(lds[rl][sl]);
  }
}

// ---------- prep: token-shift mix -> XR,XK,XV,XW bf16 ----------
__global__ __launch_bounds__(256) void k_prep4(
  const float* __restrict__ x, const float* __restrict__ shift_in,
  const float* __restrict__ mr, const float* __restrict__ mk,
  const float* __restrict__ mv, const float* __restrict__ mw,
  u16* __restrict__ xr, u16* __restrict__ xk, u16* __restrict__ xv, u16* __restrict__ xw)
{
  int idx = blockIdx.x*256 + threadIdx.x;
  int c4 = (idx & 511) * 4;
  int t  = (idx >> 9) & (TT-1);
  int b  = idx >> 19;
  size_t xo = ((size_t)(b*TT + t))*CC + c4;
  float4 xc = *(const float4*)&x[xo];
  float4 xp = (t == 0) ? *(const float4*)&shift_in[(size_t)b*CC + c4]
                       : *(const float4*)&x[xo - CC];
  float d0 = xp.x-xc.x, d1 = xp.y-xc.y, d2 = xp.z-xc.z, d3 = xp.w-xc.w;
#define MIXO(mp, op) { float4 m = *(const float4*)&mp[c4]; \
    *(ushort4*)&op[xo] = make_ushort4(f2bf(fmaf(d0,m.x,xc.x)), f2bf(fmaf(d1,m.y,xc.y)), \
                                      f2bf(fmaf(d2,m.z,xc.z)), f2bf(fmaf(d3,m.w,xc.w))); }
  MIXO(mr, xr); MIXO(mk, xk); MIXO(mv, xv); MIXO(mw, xw);
#undef MIXO
}

// ---------- GEMM body (device); 1D grid + XCD-chunked swizzle ----------
template<int AMODE>
__device__ __forceinline__ void gemm_body(
  const u16* __restrict__ Abf,
  const float* __restrict__ xg, const float* __restrict__ shiftg,
  const float* __restrict__ ma, const float* __restrict__ mg,
  const u16* __restrict__ Bt, float* __restrict__ Cf, u16* __restrict__ Cb,
  int K, int lda, int ldb, int ldc, int nx)
{
  __shared__ alignas(16) u16 sA[128*32];
  __shared__ alignas(16) u16 sB[128*32];
  const int tid = threadIdx.x;
  const int wv = tid >> 6, ln = tid & 63;
  int bx, row0;
  xcd_map(nx, bx, row0);
  const int wr = wv >> 1, wc = wv & 1;

  const float* mixv = nullptr;
  const u16* Ap = Abf;
  const u16* Btp = Bt;
  u16* Cbp = Cb;
  bool bmix = false;
  int bcol0 = bx * 128;
  int ccol0 = bx * 128;
  int ldaa = lda, ldbb = ldb, ldcc = ldc;
  int KK = K, act = 0;

  if (AMODE == 2){
    if (bx < 48){
      int sel = bx >> 4;
      Ap = Abf + (size_t)sel * 8388608u;
      Cbp = Cb + (size_t)sel * 8388608u;
      ccol0 = (bx & 15) * 128;
      ldcc = 2048; ldaa = 2048;
    } else {
      int sb = bx - 48;
      Cbp = (u16*)Cf;
      ccol0 = sb * 128;
      ldcc = 640;
      act = (sb==0) ? 1 : (sb>=3 ? 2 : 0);
      if (sb == 0){ Ap = Abf + 25165824u; ldaa = 2048; }
      else if (sb == 2){ Ap = Abf + 16777216u; ldaa = 2048; }
      else { bmix = true; mixv = (sb==1) ? ma : mg; }
    }
  }
  if (AMODE == 3){
    int sel = bx >> 4;
    Ap = Abf + sel*128;
    Btp = Bt + (size_t)sel * 262144u;
    ldbb = (sel==3) ? 256 : 128;
    KK = (sel==3) ? 256 : 128;
    const int coffs[4] = {0, 8388608, 17842176, 26230784};
    Cbp = Cb + coffs[sel];
    ccol0 = (bx & 15) * 128;
    bcol0 = ccol0;
    ldcc = 2048;
  }

  f32x4 acc[4][4] = {};
  const int ob0 = wv*2048;
  const int o0  = ob0 + ln*16;
  const int rA0 = o0 >> 6;
  const int ke0 = (o0 & 63) >> 1;
  const int ar  = tid >> 2;
  const int akc = (tid & 3) * 8;

  for (int k0 = 0; k0 < KK; k0 += 32){
    __syncthreads();
    if (AMODE != 2 || !bmix){
      gload16(&Ap[(size_t)(row0 + rA0     )*ldaa + k0 + ke0], (void*)((char*)sA + ob0));
      gload16(&Ap[(size_t)(row0 + rA0 + 16)*ldaa + k0 + ke0], (void*)((char*)sA + ob0 + 1024));
    }
    gload16(&Btp[(size_t)(bcol0 + rA0     )*ldbb + k0 + ke0], (void*)((char*)sB + ob0));
    gload16(&Btp[(size_t)(bcol0 + rA0 + 16)*ldbb + k0 + ke0], (void*)((char*)sB + ob0 + 1024));
    if (AMODE == 2 && bmix){
      float4 m0 = *(const float4*)&mixv[k0 + akc];
      float4 m1 = *(const float4*)&mixv[k0 + akc + 4];
      #pragma unroll
      for (int it = 0; it < 2; ++it){
        int r = ar + it*64;
        int gr = row0 + r;
        size_t xo = (size_t)gr*CC + k0 + akc;
        float4 c0 = *(const float4*)&xg[xo];
        float4 c1 = *(const float4*)&xg[xo + 4];
        const float* pp = ((gr & (TT-1)) == 0) ? &shiftg[(size_t)(gr >> 10)*CC + k0 + akc]
                                               : &xg[xo - CC];
        float4 p0 = *(const float4*)&pp[0];
        float4 p1 = *(const float4*)&pp[4];
        short8 vvv;
        vvv[0] = (short)f2bf(c0.x + (p0.x - c0.x)*m0.x);
        vvv[1] = (short)f2bf(c0.y + (p0.y - c0.y)*m0.y);
        vvv[2] = (short)f2bf(c0.z + (p0.z - c0.z)*m0.z);
        vvv[3] = (short)f2bf(c0.w + (p0.w - c0.w)*m0.w);
        vvv[4] = (short)f2bf(c1.x + (p1.x - c1.x)*m1.x);
        vvv[5] = (short)f2bf(c1.y + (p1.y - c1.y)*m1.y);
        vvv[6] = (short)f2bf(c1.z + (p1.z - c1.z)*m1.z);
        vvv[7] = (short)f2bf(c1.w + (p1.w - c1.w)*m1.w);
        *(short8*)&sA[r*32 + akc] = vvv;
      }
    }
    __syncthreads();
    short8 aF[4], bF[4];
    #pragma unroll
    for (int m=0;m<4;m++) aF[m] = *(const short8*)&sA[(wr*64 + m*16 + (ln&15))*32 + (ln>>4)*8];
    #pragma unroll
    for (int n=0;n<4;n++) bF[n] = *(const short8*)&sB[(wc*64 + n*16 + (ln&15))*32 + (ln>>4)*8];
    #pragma unroll
    for (int m=0;m<4;m++)
      #pragma unroll
      for (int n=0;n<4;n++)
        acc[m][n] = __builtin_amdgcn_mfma_f32_16x16x32_bf16(aF[m], bF[n], acc[m][n], 0,0,0);
  }

  const int cr = (ln >> 4) * 4, ccol = ln & 15;
  #pragma unroll
  for (int m=0;m<4;m++){
    #pragma unroll
    for (int n=0;n<4;n++){
      int gc = ccol0 + wc*64 + n*16 + ccol;
      #pragma unroll
      for (int j=0;j<4;j++){
        int gr = row0 + wr*64 + m*16 + cr + j;
        float v = acc[m][n][j];
        if (AMODE == 0){
          Cf[(size_t)gr*ldcc + gc] = v;
        } else {
          if (act == 1) v = tanhf(v);
          else if (act == 2) v = 1.f/(1.f + expf(-v));
          Cbp[(size_t)gr*ldcc + gc] = f2bf(v);
        }
      }
    }
  }
}

// named wrappers
__global__ __launch_bounds__(256) void k_gemm_rkv(
  const u16* Abf, const float* xg, const float* shiftg, const float* ma, const float* mg,
  const u16* Bt, float* Cf, u16* Cb, int K, int lda, int ldb, int ldc, int nx)
{ gemm_body<2>(Abf, xg, shiftg, ma, mg, Bt, Cf, Cb, K, lda, ldb, ldc, nx); }

__global__ __launch_bounds__(256) void k_gemm_s2(
  const u16* Abf, const float* xg, const float* shiftg, const float* ma, const float* mg,
  const u16* Bt, float* Cf, u16* Cb, int K, int lda, int ldb, int ldc, int nx)
{ gemm_body<3>(Abf, xg, shiftg, ma, mg, Bt, Cf, Cb, K, lda, ldb, ldc, nx); }

__global__ __launch_bounds__(256) void k_gemm_fin(
  const u16* Abf, const float* xg, const float* shiftg, const float* ma, const float* mg,
  const u16* Bt, float* Cf, u16* Cb, int K, int lda, int ldb, int ldc, int nx)
{ gemm_body<0>(Abf, xg, shiftg, ma, mg, Bt, Cf, Cb, K, lda, ldb, ldc, nx); }

// ---------- post1 ----------
__global__ __launch_bounds__(256) void k_post1(
  u16* __restrict__ kb, u16* __restrict__ vb, const u16* __restrict__ winb,
  u16* __restrict__ ainb, u16* __restrict__ vinb,
  const float* __restrict__ vfirst,
  const float* __restrict__ w0, const float* __restrict__ a0, const float* __restrict__ v0,
  const float* __restrict__ kkv, const float* __restrict__ kav,
  float* __restrict__ dec)
{
  int grp = blockIdx.x*4 + (threadIdx.x >> 6);
  int n = threadIdx.x & 63;
  int i = grp >> 5, h = grp & 31;
  int c = h*64 + n;
  size_t idx = (size_t)i*CC + c;
  float k  = bf2f(kb[idx]),  v = bf2f(vb[idx]);
  float wi = bf2f(winb[idx]), ai = bf2f(ainb[idx]), vi = bf2f(vinb[idx]);
  float vf = vfirst[idx];
  float a  = 1.f/(1.f + expf(-(a0[c] + ai)));
  float z  = -(w0[c] + wi);
  float sp = (z > 15.f) ? z : log1pf(expf(z));
  float decay = expf(-expf(-sp - 0.5f));
  float vg = 1.f/(1.f + expf(-(v0[c] + vi)));
  float vfin = v + (vf - v)*vg;
  float kkr = k * kkv[c];
  float ss = wave_sum64(kkr*kkr);
  float kkn = kkr / fmaxf(sqrtf(ss), 1e-12f);
  float kfin = k * (1.f + (a - 1.f)*kav[c]);
  kb[idx] = f2bf(kfin);
  vb[idx] = f2bf(vfin);
  dec[idx] = decay;
  vinb[idx] = f2bf(kkn);
  ainb[idx] = f2bf(-(kkn * a));
}

// ---------- WKV scan v7: SRSRC buffer loads, shared 32-bit voffsets, counted vmcnt ----------
// 1024 blocks = 8 row-octets x 128 (b,h); XCD(blk%8)=bh%8. Lane (rg,cg): rows
// {oct*8+rg*2,+1}, cols cg*4..+3. 2 x 8-step chunks; loads pinned by volatile asm;
// address math reduced to 3 v_add_u32/step via running voffsets (b/k/kk/r share one).
// vmcnt ledger unchanged: steady wait 56 (48 younger loads + 8 y-stores), prologue 48, tail 0.
#define SDECL(S) float4 w##S[8]; u32x2 b##S[8], k##S[8], kk##S[8], r##S[8]; u32 v##S[8];

#define SISSUE(S) do {                                                            \
  _Pragma("unroll")                                                               \
  for (int s_=0; s_<8; ++s_){                                                     \
    asm volatile("buffer_load_dwordx4 %0, %1, %2, 0 offen" : "=v"(w##S[s_])  : "v"(voW), "s"(srW) : "memory"); \
    asm volatile("buffer_load_dwordx2 %0, %1, %2, 0 offen" : "=v"(b##S[s_])  : "v"(voC), "s"(srB) : "memory"); \
    asm volatile("buffer_load_dwordx2 %0, %1, %2, 0 offen" : "=v"(k##S[s_])  : "v"(voC), "s"(srK) : "memory"); \
    asm volatile("buffer_load_dwordx2 %0, %1, %2, 0 offen" : "=v"(kk##S[s_]) : "v"(voC), "s"(srQ) : "memory"); \
    asm volatile("buffer_load_dwordx2 %0, %1, %2, 0 offen" : "=v"(r##S[s_])  : "v"(voC), "s"(srR) : "memory"); \
    asm volatile("buffer_load_dword   %0, %1, %2, 0 offen" : "=v"(v##S[s_])  : "v"(voV), "s"(srV) : "memory"); \
    voC += 4096u; voW += 8192u; voV += 4096u;                                     \
  }                                                                               \
} while(0)

#define SCHUNK(S, CNT) do {                                                       \
  asm volatile("s_waitcnt vmcnt(" #CNT ")" ::: "memory");                         \
  __builtin_amdgcn_sched_barrier(0);                                              \
  _Pragma("unroll")                                                               \
  for (int s_=0; s_<8; ++s_){                                                     \
    const float w_0=w##S[s_].x, w_1=w##S[s_].y, w_2=w##S[s_].z, w_3=w##S[s_].w;   \
    const float b_0=bflo(b##S[s_].x), b_1=bfhi(b##S[s_].x),                       \
                b_2=bflo(b##S[s_].y), b_3=bfhi(b##S[s_].y);                       \
    const float k_0=bflo(k##S[s_].x), k_1=bfhi(k##S[s_].x),                       \
                k_2=bflo(k##S[s_].y), k_3=bfhi(k##S[s_].y);                       \
    const float q_0=bflo(kk##S[s_].x), q_1=bfhi(kk##S[s_].x),                     \
                q_2=bflo(kk##S[s_].y), q_3=bfhi(kk##S[s_].y);                     \
    const float r_0=bflo(r##S[s_].x), r_1=bfhi(r##S[s_].x),                       \
                r_2=bflo(r##S[s_].y), r_3=bfhi(r##S[s_].y);                       \
    const float vv0_ = bflo(v##S[s_]);                                            \
    const float vv1_ = bfhi(v##S[s_]);                                            \
    float p0_ = fmaf(st[0][0],q_0, st[0][1]*q_1) + fmaf(st[0][2],q_2, st[0][3]*q_3); \
    float p1_ = fmaf(st[1][0],q_0, st[1][1]*q_1) + fmaf(st[1][2],q_2, st[1][3]*q_3); \
    p0_ = red16(p0_); p1_ = red16(p1_);                                           \
    st[0][0] = fmaf(st[0][0],w_0, fmaf(p0_,b_0, vv0_*k_0));                       \
    st[0][1] = fmaf(st[0][1],w_1, fmaf(p0_,b_1, vv0_*k_1));                       \
    st[0][2] = fmaf(st[0][2],w_2, fmaf(p0_,b_2, vv0_*k_2));                       \
    st[0][3] = fmaf(st[0][3],w_3, fmaf(p0_,b_3, vv0_*k_3));                       \
    st[1][0] = fmaf(st[1][0],w_0, fmaf(p1_,b_0, vv1_*k_0));                       \
    st[1][1] = fmaf(st[1][1],w_1, fmaf(p1_,b_1, vv1_*k_1));                       \
    st[1][2] = fmaf(st[1][2],w_2, fmaf(p1_,b_2, vv1_*k_2));                       \
    st[1][3] = fmaf(st[1][3],w_3, fmaf(p1_,b_3, vv1_*k_3));                       \
    float y0_ = fmaf(st[0][0],r_0, st[0][1]*r_1) + fmaf(st[0][2],r_2, st[0][3]*r_3); \
    float y1_ = fmaf(st[1][0],r_0, st[1][1]*r_1) + fmaf(st[1][2],r_2, st[1][3]*r_3); \
    y0_ = red16(y0_); y1_ = red16(y1_);                                           \
    if (cg == 0){                                                                 \
      u32 pk_ = (u32)f2bf(y0_) | ((u32)f2bf(y1_) << 16);                          \
      asm volatile("buffer_store_dword %0, %1, %2, 0 offen"                       \
                   :: "v"(pk_), "v"(voY), "s"(srY) : "memory");                   \
    }                                                                             \
    voY += 4096u;                                                                 \
  }                                                                               \
} while(0)

__global__ __launch_bounds__(64, 1) void k_scan(
  const u16* __restrict__ rb, const float* __restrict__ wb,
  const u16* __restrict__ kb, const u16* __restrict__ vb,
  const u16* __restrict__ kkb, const u16* __restrict__ bbp,
  const float* __restrict__ wkv_in, u16* __restrict__ yb, float* __restrict__ wkv_out)
{
  const int blk = blockIdx.x;
  const int bh = blk & 127, oct = blk >> 7;
  const int b = bh >> 5, h = bh & 31;
  const int ln = threadIdx.x;
  const int rg = ln >> 4;
  const int cg = ln & 15;
  const int row0 = oct*8 + rg*2;
  const int col0 = cg*4;

  float st[2][4];
  {
    const float* sp0 = &wkv_in[((size_t)bh*64 + row0    )*64 + col0];
    const float* sp1 = &wkv_in[((size_t)bh*64 + row0 + 1)*64 + col0];
    float4 a = *(const float4*)sp0, c = *(const float4*)sp1;
    st[0][0]=a.x; st[0][1]=a.y; st[0][2]=a.z; st[0][3]=a.w;
    st[1][0]=c.x; st[1][1]=c.y; st[1][2]=c.z; st[1][3]=c.w;
  }

  const size_t gc0 = ((size_t)b*TT)*CC + h*64 + col0;
  const size_t gv0 = ((size_t)b*TT)*CC + h*64 + row0;

  // buffer descriptors (SGPR quads) + running 32-bit voffsets
  const u32x4 srW = make_srsrc(wb,  33554432u);
  const u32x4 srB = make_srsrc(bbp, 16777216u);
  const u32x4 srK = make_srsrc(kb,  16777216u);
  const u32x4 srQ = make_srsrc(kkb, 16777216u);
  const u32x4 srR = make_srsrc(rb,  16777216u);
  const u32x4 srV = make_srsrc(vb,  16777216u);
  const u32x4 srY = make_srsrc(yb,  16777216u);
  u32 voC = (u32)(gc0 * 2u);
  u32 voW = (u32)(gc0 * 4u);
  u32 voV = (u32)(gv0 * 2u);
  u32 voY = (u32)(gv0 * 2u);

  SDECL(A) SDECL(B)

  SISSUE(A);
  SISSUE(B);
  SCHUNK(A, 48);
  SISSUE(A);
  SCHUNK(B, 56);
  SISSUE(B);
  for (int c = 1; c < 63; ++c){
    SCHUNK(A, 56);
    SISSUE(A);
    SCHUNK(B, 56);
    SISSUE(B);
  }
  SCHUNK(A, 56);
  SCHUNK(B, 0);

  {
    float* wo0 = &wkv_out[((size_t)bh*64 + row0    )*64 + col0];
    float* wo1 = &wkv_out[((size_t)bh*64 + row0 + 1)*64 + col0];
    *(float4*)wo0 = make_float4(st[0][0], st[0][1], st[0][2], st[0][3]);
    *(float4*)wo1 = make_float4(st[1][0], st[1][1], st[1][2], st[1][3]);
  }
}

// ---------- post2 ----------
__global__ __launch_bounds__(256) void k_post2(
  const u16* __restrict__ ybuf, const u16* __restrict__ rbuf,
  const u16* __restrict__ kfb, const u16* __restrict__ vfb,
  const u16* __restrict__ gbuf, const float* __restrict__ rk,
  const float* __restrict__ lnw, const float* __restrict__ lnb, u16* __restrict__ ao)
{
  int grp = blockIdx.x*4 + (threadIdx.x >> 6);
  int n = threadIdx.x & 63;
  int i = grp >> 5, h = grp & 31;
  int c = h*64 + n;
  size_t idx = (size_t)i*CC + c;
  float y = bf2f(ybuf[idx]);
  float s1 = wave_sum64(y);
  float s2 = wave_sum64(y*y);
  float mu = s1 * (1.f/64.f);
  float var = s2 * (1.f/64.f) - mu*mu;
  float yn = (y - mu) * rsqrtf(var + 6.4e-4f) * lnw[c] + lnb[c];
  float rv = bf2f(rbuf[idx]), kv = bf2f(kfb[idx]);
  float s3 = wave_sum64(rv * kv * rk[c]);
  float bonus = s3 * bf2f(vfb[idx]);
  ao[idx] = f2bf((yn + bonus) * bf2f(gbuf[idx]));
}

// ---------- shift_state_out = x[:, -1] (runs LAST; d_out scratch dead by then) ----------
__global__ __launch_bounds__(256) void k_shift(const float* __restrict__ x, float* __restrict__ so){
  int i = blockIdx.x*256 + threadIdx.x;
  int b = i >> 9, c4 = (i & 511)*4;
  *(float4*)&so[(size_t)b*CC + c4] = *(const float4*)&x[((size_t)(b*TT + TT-1))*CC + c4];
}

// ---------- launch ----------
extern "C" void kernel_launch(void* const* d_in, const int* in_sizes, int n_in,
                              void* d_out, int out_size, void* d_ws, size_t ws_size,
                              hipStream_t stream)
{
  const float* x        = (const float*)d_in[0];
  const float* shift_in = (const float*)d_in[1];
  const float* wkv_in   = (const float*)d_in[2];
  const float* v_first  = (const float*)d_in[3];
  const float* x_r = (const float*)d_in[4];
  const float* x_w = (const float*)d_in[5];
  const float* x_k = (const float*)d_in[6];
  const float* x_v = (const float*)d_in[7];
  const float* x_a = (const float*)d_in[8];
  const float* x_g = (const float*)d_in[9];
  const float* w0 = (const float*)d_in[10];
  const float* w1 = (const float*)d_in[11];
  const float* w2 = (const float*)d_in[12];
  const float* a0 = (const float*)d_in[13];
  const float* a1 = (const float*)d_in[14];
  const float* a2 = (const float*)d_in[15];
  const float* v0 = (const float*)d_in[16];
  const float* v1 = (const float*)d_in[17];
  const float* v2 = (const float*)d_in[18];
  const float* g1 = (const float*)d_in[19];
  const float* g2 = (const float*)d_in[20];
  const float* k_k = (const float*)d_in[21];
  const float* k_a = (const float*)d_in[22];
  const float* r_k = (const float*)d_in[23];
  const float* Wr = (const float*)d_in[24];
  const float* Wk = (const float*)d_in[25];
  const float* Wv = (const float*)d_in[26];
  const float* Wo = (const float*)d_in[27];
  const float* ln_w = (const float*)d_in[28];
  const float* ln_b = (const float*)d_in[29];

  // ---- ws layout ----
  char* ws = (char*)d_ws;
  u16* WOB  = (u16*)(ws + 0);
  u16* WRB  = (u16*)(ws + 8388608);
  u16* B2W  = (u16*)(ws + 36175872);
  u16* PBUF = (u16*)(ws + 38797312);
  u16* RB   = (u16*)(ws + 44040192);
  u16* KB   = (u16*)(ws + 60817408);
  u16* VB   = (u16*)(ws + 77594624);
  u16* YB   = (u16*)(ws + 94371840);
  float* DEC  = (float*)(ws + 8388608);
  u16* AO   = (u16*)(ws + 8388608);

  // ---- d_out scratch ----
  float* out       = (float*)d_out;
  float* shift_out = out + 8388608;
  float* wkv_out   = out + 8396800;
  float* vf_out    = out + 8921088;
  u16* XRKV = (u16*)d_out;
  u16* WINb = (u16*)d_out;
  u16* AINb = (u16*)((char*)d_out + 16777216);
  u16* VINb = (u16*)((char*)d_out + 35684352);

  // weight prep
  k_cast4<<<16384, 256, 0, stream>>>(Wr, Wk, Wv, Wo, (u16*)ws);
  k_tpadA<<<2560, 256, 0, stream>>>(w1, a1, v1, g1, w2, a2, v2, g2, (u16*)ws);

  // token-shift mix precompute
  k_prep4<<<8192, 256, 0, stream>>>(x, shift_in, x_r, x_k, x_v, x_w,
                                    XRKV, XRKV + 8388608u, XRKV + 16777216u, XRKV + 25165824u);

  // fused r/k/v + stage-1 GEMM (1D grid, XCD-chunked swizzle)
  k_gemm_rkv<<<1696, 256, 0, stream>>>(XRKV, x, shift_in, x_a, x_g,
                                       WRB, (float*)PBUF, RB, 2048, 2048, 2048, 2048, 53);

  // fused stage-2 GEMMs
  k_gemm_s2<<<2048, 256, 0, stream>>>(PBUF, nullptr, nullptr, nullptr, nullptr,
                                      B2W, nullptr, (u16*)d_out, 0, 640, 128, 2048, 64);

  // elementwise post
  k_post1<<<32768, 256, 0, stream>>>(KB, VB, WINb, AINb, VINb, v_first,
                                     w0, a0, v0, k_k, k_a, DEC);

  // sequential WKV scan (SRSRC buffer loads + running voffsets)
  k_scan<<<1024, 64, 0, stream>>>(RB, DEC, KB, VB, VINb, AINb, wkv_in, YB, wkv_out);

  // groupnorm + bonus + gate
  k_post2<<<32768, 256, 0, stream>>>(YB, RB, KB, VB, (u16*)((char*)d_out + 52461568),
                                     r_k, ln_w, ln_b, AO);

  // final GEMM -> out
  k_gemm_fin<<<512, 256, 0, stream>>>(AO, nullptr, nullptr, nullptr, nullptr,
                                      WOB, out, nullptr, 2048, 2048, 2048, 2048, 16);

  // small outputs last (XV dead; shift_out region safe now)
  k_shift<<<8, 256, 0, stream>>>(x, shift_out);
  hipMemcpyAsync(vf_out, v_first, 33554432, hipMemcpyDeviceToDevice, stream);
}

// Round 15
// 683.915 us; speedup vs baseline: 1.0824x; 1.0824x over previous
//
#include <hip/hip_runtime.h>
#include <hip/hip_bf16.h>
#include <stdint.h>

typedef unsigned short u16;
typedef unsigned int u32;
typedef unsigned long long u64;
typedef __attribute__((ext_vector_type(8))) short short8;
typedef __attribute__((ext_vector_type(4))) float f32x4;
typedef __attribute__((ext_vector_type(2))) unsigned int u32x2;

#define BB 4
#define TT 1024
#define CC 2048

// ---------- helpers ----------
__device__ __forceinline__ u16 f2bf(float f){
  __hip_bfloat16 h = __float2bfloat16(f);
  return *reinterpret_cast<u16*>(&h);
}
__device__ __forceinline__ float bf2f(u16 h){
  union { u32 u; float f; } v; v.u = ((u32)h) << 16; return v.f;
}
__device__ __forceinline__ float bflo(u32 p){
  union { u32 u; float f; } v; v.u = p << 16; return v.f;
}
__device__ __forceinline__ float bfhi(u32 p){
  union { u32 u; float f; } v; v.u = p & 0xFFFF0000u; return v.f;
}

__device__ __forceinline__ void gload16(const void* g, void* s){
  __builtin_amdgcn_global_load_lds((const __attribute__((address_space(1))) u32*)g,
                                   (__attribute__((address_space(3))) u32*)s, 16, 0, 0);
}

__device__ __forceinline__ float wave_sum64(float x){
  #pragma unroll
  for (int m = 1; m < 64; m <<= 1) x += __shfl_xor(x, m, 64);
  return x;
}

template<int N>
__device__ __forceinline__ float ror_add(float x){
  int t = __builtin_amdgcn_update_dpp(0, __builtin_bit_cast(int, x), 0x120 | N, 0xF, 0xF, false);
  return x + __builtin_bit_cast(float, t);
}
__device__ __forceinline__ float red16(float x){
  x = ror_add<8>(x); x = ror_add<4>(x); x = ror_add<2>(x); x = ror_add<1>(x);
  return x;
}

// Bijective XCD-chunked swizzle (m204), bx-major within an A-row-panel.
__device__ __forceinline__ void xcd_map(int nx, int& bx, int& row0){
  const int G = gridDim.x;
  const int q = G >> 3, r = G & 7;
  const int xcd = blockIdx.x & 7, i2 = blockIdx.x >> 3;
  const int sw = (xcd < r) ? (xcd*(q+1) + i2) : (r*(q+1) + (xcd - r)*q + i2);
  const int by = sw / nx;
  bx = sw - by*nx;
  row0 = by * 128;
}

// ---------- merged weight prep: casts (blk<16384) + tiled transposes (blk>=16384) ----------
__global__ __launch_bounds__(256) void k_wprep(
  const float* __restrict__ wr, const float* __restrict__ wk,
  const float* __restrict__ wv, const float* __restrict__ wo,
  const float* __restrict__ w1, const float* __restrict__ a1,
  const float* __restrict__ v1, const float* __restrict__ g1,
  const float* __restrict__ w2, const float* __restrict__ a2,
  const float* __restrict__ v2, const float* __restrict__ g2,
  u16* __restrict__ wsb)
{
  __shared__ float lds[32][33];
  const int blk0 = blockIdx.x;
  if (blk0 < 16384){
    int i = blk0*256 + threadIdx.x;
    int seg = i >> 20;
    int off = (i & 1048575) * 4;
    const float* src = (seg==0) ? wr : (seg==1) ? wk : (seg==2) ? wv : wo;
    const size_t dofs = (seg==0) ? 4194304u : (seg==1) ? 8388608u : (seg==2) ? 12582912u : 0u;
    float4 v = *(const float4*)&src[off];
    *(ushort4*)&wsb[dofs + off] = make_ushort4(f2bf(v.x), f2bf(v.y), f2bf(v.z), f2bf(v.w));
    return;
  }
  const int blk = blk0 - 16384;
  const float* src; int R, S, Rpad, tile, tiles_r; size_t dst;
  if      (blk <  256){ src=w1; R=2048; S=96;   Rpad=2048; dst=16777216u; tile=blk;      tiles_r=64; }
  else if (blk <  512){ src=a1; R=2048; S=96;   Rpad=2048; dst=17039360u; tile=blk-256;  tiles_r=64; }
  else if (blk <  768){ src=v1; R=2048; S=64;   Rpad=2048; dst=17301504u; tile=blk-512;  tiles_r=64; }
  else if (blk < 1280){ src=g1; R=2048; S=256;  Rpad=2048; dst=17563648u; tile=blk-768;  tiles_r=64; }
  else if (blk < 1536){ src=w2; R=96;   S=2048; Rpad=128;  dst=18087936u; tile=blk-1280; tiles_r=4;  }
  else if (blk < 1792){ src=a2; R=96;   S=2048; Rpad=128;  dst=18350080u; tile=blk-1536; tiles_r=4;  }
  else if (blk < 2048){ src=v2; R=64;   S=2048; Rpad=128;  dst=18612224u; tile=blk-1792; tiles_r=4;  }
  else                { src=g2; R=256;  S=2048; Rpad=256;  dst=18874368u; tile=blk-2048; tiles_r=8;  }
  const int tr = tile % tiles_r, ts = tile / tiles_r;
  const int r0 = tr*32, s0 = ts*32;
  const int tj = threadIdx.x & 31, ti = threadIdx.x >> 5;
  #pragma unroll
  for (int p=0;p<4;p++){
    int rr = r0 + p*8 + ti, ss = s0 + tj;
    lds[p*8+ti][tj] = (rr < R && ss < S) ? src[(size_t)rr*S + ss] : 0.f;
  }
  __syncthreads();
  #pragma unroll
  for (int p=0;p<4;p++){
    int sl = p*8 + ti, rl = tj;
    wsb[dst + (size_t)(s0+sl)*Rpad + r0 + rl] = f2bf(lds[rl][sl]);
  }
}

// ---------- prep: token-shift mix -> XR,XK,XV,XW bf16 ----------
__global__ __launch_bounds__(256) void k_prep4(
  const float* __restrict__ x, const float* __restrict__ shift_in,
  const float* __restrict__ mr, const float* __restrict__ mk,
  const float* __restrict__ mv, const float* __restrict__ mw,
  u16* __restrict__ xr, u16* __restrict__ xk, u16* __restrict__ xv, u16* __restrict__ xw)
{
  int idx = blockIdx.x*256 + threadIdx.x;
  int c4 = (idx & 511) * 4;
  int t  = (idx >> 9) & (TT-1);
  int b  = idx >> 19;
  size_t xo = ((size_t)(b*TT + t))*CC + c4;
  float4 xc = *(const float4*)&x[xo];
  float4 xp = (t == 0) ? *(const float4*)&shift_in[(size_t)b*CC + c4]
                       : *(const float4*)&x[xo - CC];
  float d0 = xp.x-xc.x, d1 = xp.y-xc.y, d2 = xp.z-xc.z, d3 = xp.w-xc.w;
#define MIXO(mp, op) { float4 m = *(const float4*)&mp[c4]; \
    *(ushort4*)&op[xo] = make_ushort4(f2bf(fmaf(d0,m.x,xc.x)), f2bf(fmaf(d1,m.y,xc.y)), \
                                      f2bf(fmaf(d2,m.z,xc.z)), f2bf(fmaf(d3,m.w,xc.w))); }
  MIXO(mr, xr); MIXO(mk, xk); MIXO(mv, xv); MIXO(mw, xw);
#undef MIXO
}

// ---------- GEMM body (device); 1D grid + XCD-chunked swizzle ----------
template<int AMODE>
__device__ __forceinline__ void gemm_body(
  const u16* __restrict__ Abf,
  const float* __restrict__ xg, const float* __restrict__ shiftg,
  const float* __restrict__ ma, const float* __restrict__ mg,
  const u16* __restrict__ Bt, float* __restrict__ Cf, u16* __restrict__ Cb,
  int K, int lda, int ldb, int ldc, int nx)
{
  __shared__ alignas(16) u16 sA[128*32];
  __shared__ alignas(16) u16 sB[128*32];
  const int tid = threadIdx.x;
  const int wv = tid >> 6, ln = tid & 63;
  int bx, row0;
  xcd_map(nx, bx, row0);
  const int wr = wv >> 1, wc = wv & 1;

  const float* mixv = nullptr;
  const u16* Ap = Abf;
  const u16* Btp = Bt;
  u16* Cbp = Cb;
  bool bmix = false;
  int bcol0 = bx * 128;
  int ccol0 = bx * 128;
  int ldaa = lda, ldbb = ldb, ldcc = ldc;
  int KK = K, act = 0;

  if (AMODE == 2){
    if (bx < 48){
      int sel = bx >> 4;
      Ap = Abf + (size_t)sel * 8388608u;
      Cbp = Cb + (size_t)sel * 8388608u;
      ccol0 = (bx & 15) * 128;
      ldcc = 2048; ldaa = 2048;
    } else {
      int sb = bx - 48;
      Cbp = (u16*)Cf;
      ccol0 = sb * 128;
      ldcc = 640;
      act = (sb==0) ? 1 : (sb>=3 ? 2 : 0);
      if (sb == 0){ Ap = Abf + 25165824u; ldaa = 2048; }
      else if (sb == 2){ Ap = Abf + 16777216u; ldaa = 2048; }
      else { bmix = true; mixv = (sb==1) ? ma : mg; }
    }
  }
  if (AMODE == 3){
    int sel = bx >> 4;
    Ap = Abf + sel*128;
    Btp = Bt + (size_t)sel * 262144u;
    ldbb = (sel==3) ? 256 : 128;
    KK = (sel==3) ? 256 : 128;
    const int coffs[4] = {0, 8388608, 17842176, 26230784};
    Cbp = Cb + coffs[sel];
    ccol0 = (bx & 15) * 128;
    bcol0 = ccol0;
    ldcc = 2048;
  }

  f32x4 acc[4][4] = {};
  const int ob0 = wv*2048;
  const int o0  = ob0 + ln*16;
  const int rA0 = o0 >> 6;
  const int ke0 = (o0 & 63) >> 1;
  const int ar  = tid >> 2;
  const int akc = (tid & 3) * 8;

  for (int k0 = 0; k0 < KK; k0 += 32){
    __syncthreads();
    if (AMODE != 2 || !bmix){
      gload16(&Ap[(size_t)(row0 + rA0     )*ldaa + k0 + ke0], (void*)((char*)sA + ob0));
      gload16(&Ap[(size_t)(row0 + rA0 + 16)*ldaa + k0 + ke0], (void*)((char*)sA + ob0 + 1024));
    }
    gload16(&Btp[(size_t)(bcol0 + rA0     )*ldbb + k0 + ke0], (void*)((char*)sB + ob0));
    gload16(&Btp[(size_t)(bcol0 + rA0 + 16)*ldbb + k0 + ke0], (void*)((char*)sB + ob0 + 1024));
    if (AMODE == 2 && bmix){
      float4 m0 = *(const float4*)&mixv[k0 + akc];
      float4 m1 = *(const float4*)&mixv[k0 + akc + 4];
      #pragma unroll
      for (int it = 0; it < 2; ++it){
        int r = ar + it*64;
        int gr = row0 + r;
        size_t xo = (size_t)gr*CC + k0 + akc;
        float4 c0 = *(const float4*)&xg[xo];
        float4 c1 = *(const float4*)&xg[xo + 4];
        const float* pp = ((gr & (TT-1)) == 0) ? &shiftg[(size_t)(gr >> 10)*CC + k0 + akc]
                                               : &xg[xo - CC];
        float4 p0 = *(const float4*)&pp[0];
        float4 p1 = *(const float4*)&pp[4];
        short8 vvv;
        vvv[0] = (short)f2bf(c0.x + (p0.x - c0.x)*m0.x);
        vvv[1] = (short)f2bf(c0.y + (p0.y - c0.y)*m0.y);
        vvv[2] = (short)f2bf(c0.z + (p0.z - c0.z)*m0.z);
        vvv[3] = (short)f2bf(c0.w + (p0.w - c0.w)*m0.w);
        vvv[4] = (short)f2bf(c1.x + (p1.x - c1.x)*m1.x);
        vvv[5] = (short)f2bf(c1.y + (p1.y - c1.y)*m1.y);
        vvv[6] = (short)f2bf(c1.z + (p1.z - c1.z)*m1.z);
        vvv[7] = (short)f2bf(c1.w + (p1.w - c1.w)*m1.w);
        *(short8*)&sA[r*32 + akc] = vvv;
      }
    }
    __syncthreads();
    short8 aF[4], bF[4];
    #pragma unroll
    for (int m=0;m<4;m++) aF[m] = *(const short8*)&sA[(wr*64 + m*16 + (ln&15))*32 + (ln>>4)*8];
    #pragma unroll
    for (int n=0;n<4;n++) bF[n] = *(const short8*)&sB[(wc*64 + n*16 + (ln&15))*32 + (ln>>4)*8];
    #pragma unroll
    for (int m=0;m<4;m++)
      #pragma unroll
      for (int n=0;n<4;n++)
        acc[m][n] = __builtin_amdgcn_mfma_f32_16x16x32_bf16(aF[m], bF[n], acc[m][n], 0,0,0);
  }

  const int cr = (ln >> 4) * 4, ccol = ln & 15;
  #pragma unroll
  for (int m=0;m<4;m++){
    #pragma unroll
    for (int n=0;n<4;n++){
      int gc = ccol0 + wc*64 + n*16 + ccol;
      #pragma unroll
      for (int j=0;j<4;j++){
        int gr = row0 + wr*64 + m*16 + cr + j;
        float v = acc[m][n][j];
        if (AMODE == 0){
          Cf[(size_t)gr*ldcc + gc] = v;
        } else {
          if (act == 1) v = tanhf(v);
          else if (act == 2) v = 1.f/(1.f + expf(-v));
          Cbp[(size_t)gr*ldcc + gc] = f2bf(v);
        }
      }
    }
  }
}

// named wrappers
__global__ __launch_bounds__(256) void k_gemm_rkv(
  const u16* Abf, const float* xg, const float* shiftg, const float* ma, const float* mg,
  const u16* Bt, float* Cf, u16* Cb, int K, int lda, int ldb, int ldc, int nx)
{ gemm_body<2>(Abf, xg, shiftg, ma, mg, Bt, Cf, Cb, K, lda, ldb, ldc, nx); }

__global__ __launch_bounds__(256) void k_gemm_s2(
  const u16* Abf, const float* xg, const float* shiftg, const float* ma, const float* mg,
  const u16* Bt, float* Cf, u16* Cb, int K, int lda, int ldb, int ldc, int nx)
{ gemm_body<3>(Abf, xg, shiftg, ma, mg, Bt, Cf, Cb, K, lda, ldb, ldc, nx); }

__global__ __launch_bounds__(256) void k_gemm_fin(
  const u16* Abf, const float* xg, const float* shiftg, const float* ma, const float* mg,
  const u16* Bt, float* Cf, u16* Cb, int K, int lda, int ldb, int ldc, int nx)
{ gemm_body<0>(Abf, xg, shiftg, ma, mg, Bt, Cf, Cb, K, lda, ldb, ldc, nx); }

// ---------- post1 ----------
__global__ __launch_bounds__(256) void k_post1(
  u16* __restrict__ kb, u16* __restrict__ vb, const u16* __restrict__ winb,
  u16* __restrict__ ainb, u16* __restrict__ vinb,
  const float* __restrict__ vfirst,
  const float* __restrict__ w0, const float* __restrict__ a0, const float* __restrict__ v0,
  const float* __restrict__ kkv, const float* __restrict__ kav,
  float* __restrict__ dec)
{
  int grp = blockIdx.x*4 + (threadIdx.x >> 6);
  int n = threadIdx.x & 63;
  int i = grp >> 5, h = grp & 31;
  int c = h*64 + n;
  size_t idx = (size_t)i*CC + c;
  float k  = bf2f(kb[idx]),  v = bf2f(vb[idx]);
  float wi = bf2f(winb[idx]), ai = bf2f(ainb[idx]), vi = bf2f(vinb[idx]);
  float vf = vfirst[idx];
  float a  = 1.f/(1.f + expf(-(a0[c] + ai)));
  float z  = -(w0[c] + wi);
  float sp = (z > 15.f) ? z : log1pf(expf(z));
  float decay = expf(-expf(-sp - 0.5f));
  float vg = 1.f/(1.f + expf(-(v0[c] + vi)));
  float vfin = v + (vf - v)*vg;
  float kkr = k * kkv[c];
  float ss = wave_sum64(kkr*kkr);
  float kkn = kkr / fmaxf(sqrtf(ss), 1e-12f);
  float kfin = k * (1.f + (a - 1.f)*kav[c]);
  kb[idx] = f2bf(kfin);
  vb[idx] = f2bf(vfin);
  dec[idx] = decay;
  vinb[idx] = f2bf(kkn);
  ainb[idx] = f2bf(-(kkn * a));
}

// ---------- WKV scan v6 (measured best): asm-pinned prefetch, 2 x 8-step chunks ----------
#define SDECL(S) float4 w##S[8]; u32x2 b##S[8], k##S[8], kk##S[8], r##S[8]; u32 v##S[8];

#define SISSUE(S, t0) do {                                                        \
  _Pragma("unroll")                                                               \
  for (int s_=0; s_<8; ++s_){                                                     \
    u64 ow = (u64)(uintptr_t)&wb [gc0 + (size_t)((t0)+s_)*CC];                    \
    u64 ob = (u64)(uintptr_t)&bbp[gc0 + (size_t)((t0)+s_)*CC];                    \
    u64 ok = (u64)(uintptr_t)&kb [gc0 + (size_t)((t0)+s_)*CC];                    \
    u64 oq = (u64)(uintptr_t)&kkb[gc0 + (size_t)((t0)+s_)*CC];                    \
    u64 orr= (u64)(uintptr_t)&rb [gc0 + (size_t)((t0)+s_)*CC];                    \
    u64 ov = (u64)(uintptr_t)&vb [gv0 + (size_t)((t0)+s_)*CC];                    \
    asm volatile("global_load_dwordx4 %0, %1, off" : "=v"(w##S[s_])  : "v"(ow) : "memory"); \
    asm volatile("global_load_dwordx2 %0, %1, off" : "=v"(b##S[s_])  : "v"(ob) : "memory"); \
    asm volatile("global_load_dwordx2 %0, %1, off" : "=v"(k##S[s_])  : "v"(ok) : "memory"); \
    asm volatile("global_load_dwordx2 %0, %1, off" : "=v"(kk##S[s_]) : "v"(oq) : "memory"); \
    asm volatile("global_load_dwordx2 %0, %1, off" : "=v"(r##S[s_])  : "v"(orr): "memory"); \
    asm volatile("global_load_dword   %0, %1, off" : "=v"(v##S[s_])  : "v"(ov) : "memory"); \
  }                                                                               \
} while(0)

#define SCHUNK(S, t0, CNT) do {                                                   \
  asm volatile("s_waitcnt vmcnt(" #CNT ")" ::: "memory");                         \
  __builtin_amdgcn_sched_barrier(0);                                              \
  _Pragma("unroll")                                                               \
  for (int s_=0; s_<8; ++s_){                                                     \
    const float w_0=w##S[s_].x, w_1=w##S[s_].y, w_2=w##S[s_].z, w_3=w##S[s_].w;   \
    const float b_0=bflo(b##S[s_].x), b_1=bfhi(b##S[s_].x),                       \
                b_2=bflo(b##S[s_].y), b_3=bfhi(b##S[s_].y);                       \
    const float k_0=bflo(k##S[s_].x), k_1=bfhi(k##S[s_].x),                       \
                k_2=bflo(k##S[s_].y), k_3=bfhi(k##S[s_].y);                       \
    const float q_0=bflo(kk##S[s_].x), q_1=bfhi(kk##S[s_].x),                     \
                q_2=bflo(kk##S[s_].y), q_3=bfhi(kk##S[s_].y);                     \
    const float r_0=bflo(r##S[s_].x), r_1=bfhi(r##S[s_].x),                       \
                r_2=bflo(r##S[s_].y), r_3=bfhi(r##S[s_].y);                       \
    const float vv0_ = bflo(v##S[s_]);                                            \
    const float vv1_ = bfhi(v##S[s_]);                                            \
    float p0_ = fmaf(st[0][0],q_0, st[0][1]*q_1) + fmaf(st[0][2],q_2, st[0][3]*q_3); \
    float p1_ = fmaf(st[1][0],q_0, st[1][1]*q_1) + fmaf(st[1][2],q_2, st[1][3]*q_3); \
    p0_ = red16(p0_); p1_ = red16(p1_);                                           \
    st[0][0] = fmaf(st[0][0],w_0, fmaf(p0_,b_0, vv0_*k_0));                       \
    st[0][1] = fmaf(st[0][1],w_1, fmaf(p0_,b_1, vv0_*k_1));                       \
    st[0][2] = fmaf(st[0][2],w_2, fmaf(p0_,b_2, vv0_*k_2));                       \
    st[0][3] = fmaf(st[0][3],w_3, fmaf(p0_,b_3, vv0_*k_3));                       \
    st[1][0] = fmaf(st[1][0],w_0, fmaf(p1_,b_0, vv1_*k_0));                       \
    st[1][1] = fmaf(st[1][1],w_1, fmaf(p1_,b_1, vv1_*k_1));                       \
    st[1][2] = fmaf(st[1][2],w_2, fmaf(p1_,b_2, vv1_*k_2));                       \
    st[1][3] = fmaf(st[1][3],w_3, fmaf(p1_,b_3, vv1_*k_3));                       \
    float y0_ = fmaf(st[0][0],r_0, st[0][1]*r_1) + fmaf(st[0][2],r_2, st[0][3]*r_3); \
    float y1_ = fmaf(st[1][0],r_0, st[1][1]*r_1) + fmaf(st[1][2],r_2, st[1][3]*r_3); \
    y0_ = red16(y0_); y1_ = red16(y1_);                                           \
    if (cg == 0){                                                                 \
      u32 pk_ = (u32)f2bf(y0_) | ((u32)f2bf(y1_) << 16);                          \
      *(u32*)&yb[gv0 + (size_t)((t0)+s_)*CC] = pk_;                               \
    }                                                                             \
  }                                                                               \
} while(0)

__global__ __launch_bounds__(64, 1) void k_scan(
  const u16* __restrict__ rb, const float* __restrict__ wb,
  const u16* __restrict__ kb, const u16* __restrict__ vb,
  const u16* __restrict__ kkb, const u16* __restrict__ bbp,
  const float* __restrict__ wkv_in, u16* __restrict__ yb, float* __restrict__ wkv_out)
{
  const int blk = blockIdx.x;
  const int bh = blk & 127, oct = blk >> 7;
  const int b = bh >> 5, h = bh & 31;
  const int ln = threadIdx.x;
  const int rg = ln >> 4;
  const int cg = ln & 15;
  const int row0 = oct*8 + rg*2;
  const int col0 = cg*4;

  float st[2][4];
  {
    const float* sp0 = &wkv_in[((size_t)bh*64 + row0    )*64 + col0];
    const float* sp1 = &wkv_in[((size_t)bh*64 + row0 + 1)*64 + col0];
    float4 a = *(const float4*)sp0, c = *(const float4*)sp1;
    st[0][0]=a.x; st[0][1]=a.y; st[0][2]=a.z; st[0][3]=a.w;
    st[1][0]=c.x; st[1][1]=c.y; st[1][2]=c.z; st[1][3]=c.w;
  }

  const size_t gc0 = ((size_t)b*TT)*CC + h*64 + col0;
  const size_t gv0 = ((size_t)b*TT)*CC + h*64 + row0;

  SDECL(A) SDECL(B)

  SISSUE(A, 0);
  SISSUE(B, 8);
  SCHUNK(A, 0, 48);
  SISSUE(A, 16);
  SCHUNK(B, 8, 56);
  SISSUE(B, 24);
  for (int c = 1; c < 63; ++c){
    const int t0 = c*16;
    SCHUNK(A, t0, 56);
    SISSUE(A, t0+16);
    SCHUNK(B, t0+8, 56);
    SISSUE(B, t0+24);
  }
  SCHUNK(A, 1008, 56);
  SCHUNK(B, 1016, 0);

  {
    float* wo0 = &wkv_out[((size_t)bh*64 + row0    )*64 + col0];
    float* wo1 = &wkv_out[((size_t)bh*64 + row0 + 1)*64 + col0];
    *(float4*)wo0 = make_float4(st[0][0], st[0][1], st[0][2], st[0][3]);
    *(float4*)wo1 = make_float4(st[1][0], st[1][1], st[1][2], st[1][3]);
  }
}

// ---------- post2 ----------
__global__ __launch_bounds__(256) void k_post2(
  const u16* __restrict__ ybuf, const u16* __restrict__ rbuf,
  const u16* __restrict__ kfb, const u16* __restrict__ vfb,
  const u16* __restrict__ gbuf, const float* __restrict__ rk,
  const float* __restrict__ lnw, const float* __restrict__ lnb, u16* __restrict__ ao)
{
  int grp = blockIdx.x*4 + (threadIdx.x >> 6);
  int n = threadIdx.x & 63;
  int i = grp >> 5, h = grp & 31;
  int c = h*64 + n;
  size_t idx = (size_t)i*CC + c;
  float y = bf2f(ybuf[idx]);
  float s1 = wave_sum64(y);
  float s2 = wave_sum64(y*y);
  float mu = s1 * (1.f/64.f);
  float var = s2 * (1.f/64.f) - mu*mu;
  float yn = (y - mu) * rsqrtf(var + 6.4e-4f) * lnw[c] + lnb[c];
  float rv = bf2f(rbuf[idx]), kv = bf2f(kfb[idx]);
  float s3 = wave_sum64(rv * kv * rk[c]);
  float bonus = s3 * bf2f(vfb[idx]);
  ao[idx] = f2bf((yn + bonus) * bf2f(gbuf[idx]));
}

// ---------- shift_state_out = x[:, -1] (runs LAST; d_out scratch dead by then) ----------
__global__ __launch_bounds__(256) void k_shift(const float* __restrict__ x, float* __restrict__ so){
  int i = blockIdx.x*256 + threadIdx.x;
  int b = i >> 9, c4 = (i & 511)*4;
  *(float4*)&so[(size_t)b*CC + c4] = *(const float4*)&x[((size_t)(b*TT + TT-1))*CC + c4];
}

// ---------- launch ----------
extern "C" void kernel_launch(void* const* d_in, const int* in_sizes, int n_in,
                              void* d_out, int out_size, void* d_ws, size_t ws_size,
                              hipStream_t stream)
{
  const float* x        = (const float*)d_in[0];
  const float* shift_in = (const float*)d_in[1];
  const float* wkv_in   = (const float*)d_in[2];
  const float* v_first  = (const float*)d_in[3];
  const float* x_r = (const float*)d_in[4];
  const float* x_w = (const float*)d_in[5];
  const float* x_k = (const float*)d_in[6];
  const float* x_v = (const float*)d_in[7];
  const float* x_a = (const float*)d_in[8];
  const float* x_g = (const float*)d_in[9];
  const float* w0 = (const float*)d_in[10];
  const float* w1 = (const float*)d_in[11];
  const float* w2 = (const float*)d_in[12];
  const float* a0 = (const float*)d_in[13];
  const float* a1 = (const float*)d_in[14];
  const float* a2 = (const float*)d_in[15];
  const float* v0 = (const float*)d_in[16];
  const float* v1 = (const float*)d_in[17];
  const float* v2 = (const float*)d_in[18];
  const float* g1 = (const float*)d_in[19];
  const float* g2 = (const float*)d_in[20];
  const float* k_k = (const float*)d_in[21];
  const float* k_a = (const float*)d_in[22];
  const float* r_k = (const float*)d_in[23];
  const float* Wr = (const float*)d_in[24];
  const float* Wk = (const float*)d_in[25];
  const float* Wv = (const float*)d_in[26];
  const float* Wo = (const float*)d_in[27];
  const float* ln_w = (const float*)d_in[28];
  const float* ln_b = (const float*)d_in[29];

  // ---- ws layout ----
  char* ws = (char*)d_ws;
  u16* WOB  = (u16*)(ws + 0);
  u16* WRB  = (u16*)(ws + 8388608);
  u16* B2W  = (u16*)(ws + 36175872);
  u16* PBUF = (u16*)(ws + 38797312);
  u16* RB   = (u16*)(ws + 44040192);
  u16* KB   = (u16*)(ws + 60817408);
  u16* VB   = (u16*)(ws + 77594624);
  u16* YB   = (u16*)(ws + 94371840);
  float* DEC  = (float*)(ws + 8388608);
  u16* AO   = (u16*)(ws + 8388608);

  // ---- d_out scratch ----
  float* out       = (float*)d_out;
  float* shift_out = out + 8388608;
  float* wkv_out   = out + 8396800;
  float* vf_out    = out + 8921088;
  u16* XRKV = (u16*)d_out;
  u16* WINb = (u16*)d_out;
  u16* AINb = (u16*)((char*)d_out + 16777216);
  u16* VINb = (u16*)((char*)d_out + 35684352);

  // merged weight prep (casts + transposes, one launch)
  k_wprep<<<18944, 256, 0, stream>>>(Wr, Wk, Wv, Wo, w1, a1, v1, g1, w2, a2, v2, g2, (u16*)ws);

  // token-shift mix precompute
  k_prep4<<<8192, 256, 0, stream>>>(x, shift_in, x_r, x_k, x_v, x_w,
                                    XRKV, XRKV + 8388608u, XRKV + 16777216u, XRKV + 25165824u);

  // fused r/k/v + stage-1 GEMM (1D grid, XCD-chunked swizzle)
  k_gemm_rkv<<<1696, 256, 0, stream>>>(XRKV, x, shift_in, x_a, x_g,
                                       WRB, (float*)PBUF, RB, 2048, 2048, 2048, 2048, 53);

  // fused stage-2 GEMMs
  k_gemm_s2<<<2048, 256, 0, stream>>>(PBUF, nullptr, nullptr, nullptr, nullptr,
                                      B2W, nullptr, (u16*)d_out, 0, 640, 128, 2048, 64);

  // elementwise post
  k_post1<<<32768, 256, 0, stream>>>(KB, VB, WINb, AINb, VINb, v_first,
                                     w0, a0, v0, k_k, k_a, DEC);

  // sequential WKV scan (v6: asm-pinned prefetch, counted vmcnt)
  k_scan<<<1024, 64, 0, stream>>>(RB, DEC, KB, VB, VINb, AINb, wkv_in, YB, wkv_out);

  // groupnorm + bonus + gate
  k_post2<<<32768, 256, 0, stream>>>(YB, RB, KB, VB, (u16*)((char*)d_out + 52461568),
                                     r_k, ln_w, ln_b, AO);

  // final GEMM -> out
  k_gemm_fin<<<512, 256, 0, stream>>>(AO, nullptr, nullptr, nullptr, nullptr,
                                      WOB, out, nullptr, 2048, 2048, 2048, 2048, 16);

  // small outputs last (XV dead; shift_out region safe now)
  k_shift<<<8, 256, 0, stream>>>(x, shift_out);
  hipMemcpyAsync(vf_out, v_first, 33554432, hipMemcpyDeviceToDevice, stream);
}

// Round 16
// 666.478 us; speedup vs baseline: 1.1107x; 1.0262x over previous
//
#include <hip/hip_runtime.h>
#include <hip/hip_bf16.h>
#include <stdint.h>

typedef unsigned short u16;
typedef unsigned int u32;
typedef unsigned long long u64;
typedef __attribute__((ext_vector_type(8))) short short8;
typedef __attribute__((ext_vector_type(4))) float f32x4;
typedef __attribute__((ext_vector_type(2))) unsigned int u32x2;

#define BB 4
#define TT 1024
#define CC 2048

// ---------- helpers ----------
__device__ __forceinline__ u16 f2bf(float f){
  __hip_bfloat16 h = __float2bfloat16(f);
  return *reinterpret_cast<u16*>(&h);
}
__device__ __forceinline__ float bf2f(u16 h){
  union { u32 u; float f; } v; v.u = ((u32)h) << 16; return v.f;
}
__device__ __forceinline__ float bflo(u32 p){
  union { u32 u; float f; } v; v.u = p << 16; return v.f;
}
__device__ __forceinline__ float bfhi(u32 p){
  union { u32 u; float f; } v; v.u = p & 0xFFFF0000u; return v.f;
}

__device__ __forceinline__ void gload16(const void* g, void* s){
  __builtin_amdgcn_global_load_lds((const __attribute__((address_space(1))) u32*)g,
                                   (__attribute__((address_space(3))) u32*)s, 16, 0, 0);
}

__device__ __forceinline__ float wave_sum64(float x){
  #pragma unroll
  for (int m = 1; m < 64; m <<= 1) x += __shfl_xor(x, m, 64);
  return x;
}

template<int N>
__device__ __forceinline__ float ror_add(float x){
  int t = __builtin_amdgcn_update_dpp(0, __builtin_bit_cast(int, x), 0x120 | N, 0xF, 0xF, false);
  return x + __builtin_bit_cast(float, t);
}
__device__ __forceinline__ float red16(float x){
  x = ror_add<8>(x); x = ror_add<4>(x); x = ror_add<2>(x); x = ror_add<1>(x);
  return x;
}

// Bijective XCD-chunked swizzle (m204), bx-major within an A-row-panel.
__device__ __forceinline__ void xcd_map(int nx, int& bx, int& row0){
  const int G = gridDim.x;
  const int q = G >> 3, r = G & 7;
  const int xcd = blockIdx.x & 7, i2 = blockIdx.x >> 3;
  const int sw = (xcd < r) ? (xcd*(q+1) + i2) : (r*(q+1) + (xcd - r)*q + i2);
  const int by = sw / nx;
  bx = sw - by*nx;
  row0 = by * 128;
}

// ---------- merged weight prep: casts (blk<16384) + tiled transposes (blk>=16384) ----------
__global__ __launch_bounds__(256) void k_wprep(
  const float* __restrict__ wr, const float* __restrict__ wk,
  const float* __restrict__ wv, const float* __restrict__ wo,
  const float* __restrict__ w1, const float* __restrict__ a1,
  const float* __restrict__ v1, const float* __restrict__ g1,
  const float* __restrict__ w2, const float* __restrict__ a2,
  const float* __restrict__ v2, const float* __restrict__ g2,
  u16* __restrict__ wsb)
{
  __shared__ float lds[32][33];
  const int blk0 = blockIdx.x;
  if (blk0 < 16384){
    int i = blk0*256 + threadIdx.x;
    int seg = i >> 20;
    int off = (i & 1048575) * 4;
    const float* src = (seg==0) ? wr : (seg==1) ? wk : (seg==2) ? wv : wo;
    const size_t dofs = (seg==0) ? 4194304u : (seg==1) ? 8388608u : (seg==2) ? 12582912u : 0u;
    float4 v = *(const float4*)&src[off];
    *(ushort4*)&wsb[dofs + off] = make_ushort4(f2bf(v.x), f2bf(v.y), f2bf(v.z), f2bf(v.w));
    return;
  }
  const int blk = blk0 - 16384;
  const float* src; int R, S, Rpad, tile, tiles_r; size_t dst;
  if      (blk <  256){ src=w1; R=2048; S=96;   Rpad=2048; dst=16777216u; tile=blk;      tiles_r=64; }
  else if (blk <  512){ src=a1; R=2048; S=96;   Rpad=2048; dst=17039360u; tile=blk-256;  tiles_r=64; }
  else if (blk <  768){ src=v1; R=2048; S=64;   Rpad=2048; dst=17301504u; tile=blk-512;  tiles_r=64; }
  else if (blk < 1280){ src=g1; R=2048; S=256;  Rpad=2048; dst=17563648u; tile=blk-768;  tiles_r=64; }
  else if (blk < 1536){ src=w2; R=96;   S=2048; Rpad=128;  dst=18087936u; tile=blk-1280; tiles_r=4;  }
  else if (blk < 1792){ src=a2; R=96;   S=2048; Rpad=128;  dst=18350080u; tile=blk-1536; tiles_r=4;  }
  else if (blk < 2048){ src=v2; R=64;   S=2048; Rpad=128;  dst=18612224u; tile=blk-1792; tiles_r=4;  }
  else                { src=g2; R=256;  S=2048; Rpad=256;  dst=18874368u; tile=blk-2048; tiles_r=8;  }
  const int tr = tile % tiles_r, ts = tile / tiles_r;
  const int r0 = tr*32, s0 = ts*32;
  const int tj = threadIdx.x & 31, ti = threadIdx.x >> 5;
  #pragma unroll
  for (int p=0;p<4;p++){
    int rr = r0 + p*8 + ti, ss = s0 + tj;
    lds[p*8+ti][tj] = (rr < R && ss < S) ? src[(size_t)rr*S + ss] : 0.f;
  }
  __syncthreads();
  #pragma unroll
  for (int p=0;p<4;p++){
    int sl = p*8 + ti, rl = tj;
    wsb[dst + (size_t)(s0+sl)*Rpad + r0 + rl] = f2bf(lds[rl][sl]);
  }
}

// ---------- prep: token-shift mix -> XR,XK,XV,XW bf16 ----------
__global__ __launch_bounds__(256) void k_prep4(
  const float* __restrict__ x, const float* __restrict__ shift_in,
  const float* __restrict__ mr, const float* __restrict__ mk,
  const float* __restrict__ mv, const float* __restrict__ mw,
  u16* __restrict__ xr, u16* __restrict__ xk, u16* __restrict__ xv, u16* __restrict__ xw)
{
  int idx = blockIdx.x*256 + threadIdx.x;
  int c4 = (idx & 511) * 4;
  int t  = (idx >> 9) & (TT-1);
  int b  = idx >> 19;
  size_t xo = ((size_t)(b*TT + t))*CC + c4;
  float4 xc = *(const float4*)&x[xo];
  float4 xp = (t == 0) ? *(const float4*)&shift_in[(size_t)b*CC + c4]
                       : *(const float4*)&x[xo - CC];
  float d0 = xp.x-xc.x, d1 = xp.y-xc.y, d2 = xp.z-xc.z, d3 = xp.w-xc.w;
#define MIXO(mp, op) { float4 m = *(const float4*)&mp[c4]; \
    *(ushort4*)&op[xo] = make_ushort4(f2bf(fmaf(d0,m.x,xc.x)), f2bf(fmaf(d1,m.y,xc.y)), \
                                      f2bf(fmaf(d2,m.z,xc.z)), f2bf(fmaf(d3,m.w,xc.w))); }
  MIXO(mr, xr); MIXO(mk, xk); MIXO(mv, xv); MIXO(mw, xw);
#undef MIXO
}

// ---------- GEMM body: 128x128 tile, BK=64, both-sides XOR swizzle, XCD-chunked ----------
// LDS linear dest for global_load_lds; global source column pre-swizzled per lane;
// ds_read applies the same XOR ((ln&7)<<3 elems) => conflict-free b128 reads.
template<int AMODE>
__device__ __forceinline__ void gemm_body(
  const u16* __restrict__ Abf,
  const float* __restrict__ xg, const float* __restrict__ shiftg,
  const float* __restrict__ ma, const float* __restrict__ mg,
  const u16* __restrict__ Bt, float* __restrict__ Cf, u16* __restrict__ Cb,
  int K, int lda, int ldb, int ldc, int nx)
{
  __shared__ alignas(16) u16 sA[128*64];
  __shared__ alignas(16) u16 sB[128*64];
  const int tid = threadIdx.x;
  const int wv = tid >> 6, ln = tid & 63;
  int bx, row0;
  xcd_map(nx, bx, row0);
  const int wr = wv >> 1, wc = wv & 1;

  const float* mixv = nullptr;
  const u16* Ap = Abf;
  const u16* Btp = Bt;
  u16* Cbp = Cb;
  bool bmix = false;
  int bcol0 = bx * 128;
  int ccol0 = bx * 128;
  int ldaa = lda, ldbb = ldb, ldcc = ldc;
  int KK = K, act = 0;

  if (AMODE == 2){
    if (bx < 48){
      int sel = bx >> 4;
      Ap = Abf + (size_t)sel * 8388608u;
      Cbp = Cb + (size_t)sel * 8388608u;
      ccol0 = (bx & 15) * 128;
      ldcc = 2048; ldaa = 2048;
    } else {
      int sb = bx - 48;
      Cbp = (u16*)Cf;
      ccol0 = sb * 128;
      ldcc = 640;
      act = (sb==0) ? 1 : (sb>=3 ? 2 : 0);
      if (sb == 0){ Ap = Abf + 25165824u; ldaa = 2048; }
      else if (sb == 2){ Ap = Abf + 16777216u; ldaa = 2048; }
      else { bmix = true; mixv = (sb==1) ? ma : mg; }
    }
  }
  if (AMODE == 3){
    int sel = bx >> 4;
    Ap = Abf + sel*128;
    Btp = Bt + (size_t)sel * 262144u;
    ldbb = (sel==3) ? 256 : 128;
    KK = (sel==3) ? 256 : 128;
    const int coffs[4] = {0, 8388608, 17842176, 26230784};
    Cbp = Cb + coffs[sel];
    ccol0 = (bx & 15) * 128;
    bcol0 = ccol0;
    ldcc = 2048;
  }

  f32x4 acc[4][4] = {};
  // staging geometry (BK=64): wave wv covers rows wv*32..+31; load j covers rows +j*8.
  const int srow = ln >> 3;                     // row within 8-row group
  const int scol = ((ln & 7) ^ srow) * 8;       // PRE-SWIZZLED global col (elems)
  const int ob0  = wv * 4096;                   // wave LDS byte base
  const int rsw  = (ln & 7) << 3;               // read-side XOR (elems)

  for (int k0 = 0; k0 < KK; k0 += 64){
    __syncthreads();
    if (AMODE != 2 || !bmix){
      #pragma unroll
      for (int j=0;j<4;j++)
        gload16(&Ap[(size_t)(row0 + wv*32 + j*8 + srow)*ldaa + k0 + scol],
                (void*)((char*)sA + ob0 + j*1024));
    }
    #pragma unroll
    for (int j=0;j<4;j++)
      gload16(&Btp[(size_t)(bcol0 + wv*32 + j*8 + srow)*ldbb + k0 + scol],
              (void*)((char*)sB + ob0 + j*1024));
    if (AMODE == 2 && bmix){
      const int r_  = tid >> 2;
      const int akc = (tid & 3) * 8;
      #pragma unroll
      for (int kb2 = 0; kb2 < 64; kb2 += 32){
        float4 m0 = *(const float4*)&mixv[k0 + kb2 + akc];
        float4 m1 = *(const float4*)&mixv[k0 + kb2 + akc + 4];
        #pragma unroll
        for (int it = 0; it < 2; ++it){
          int r = r_ + it*64;
          int gr = row0 + r;
          size_t xo = (size_t)gr*CC + k0 + kb2 + akc;
          float4 c0 = *(const float4*)&xg[xo];
          float4 c1 = *(const float4*)&xg[xo + 4];
          const float* pp = ((gr & (TT-1)) == 0) ? &shiftg[(size_t)(gr >> 10)*CC + k0 + kb2 + akc]
                                                 : &xg[xo - CC];
          float4 p0 = *(const float4*)&pp[0];
          float4 p1 = *(const float4*)&pp[4];
          short8 vvv;
          vvv[0] = (short)f2bf(c0.x + (p0.x - c0.x)*m0.x);
          vvv[1] = (short)f2bf(c0.y + (p0.y - c0.y)*m0.y);
          vvv[2] = (short)f2bf(c0.z + (p0.z - c0.z)*m0.z);
          vvv[3] = (short)f2bf(c0.w + (p0.w - c0.w)*m0.w);
          vvv[4] = (short)f2bf(c1.x + (p1.x - c1.x)*m1.x);
          vvv[5] = (short)f2bf(c1.y + (p1.y - c1.y)*m1.y);
          vvv[6] = (short)f2bf(c1.z + (p1.z - c1.z)*m1.z);
          vvv[7] = (short)f2bf(c1.w + (p1.w - c1.w)*m1.w);
          int csw = (kb2 + akc) ^ ((r & 7) << 3);
          *(short8*)&sA[r*64 + csw] = vvv;
        }
      }
    }
    __syncthreads();
    #pragma unroll
    for (int kk = 0; kk < 2; ++kk){
      short8 aF[4], bF[4];
      #pragma unroll
      for (int m=0;m<4;m++){
        int rr = wr*64 + m*16 + (ln&15);
        aF[m] = *(const short8*)&sA[rr*64 + ((kk*32 + (ln>>4)*8) ^ rsw)];
      }
      #pragma unroll
      for (int n=0;n<4;n++){
        int rr = wc*64 + n*16 + (ln&15);
        bF[n] = *(const short8*)&sB[rr*64 + ((kk*32 + (ln>>4)*8) ^ rsw)];
      }
      #pragma unroll
      for (int m=0;m<4;m++)
        #pragma unroll
        for (int n=0;n<4;n++)
          acc[m][n] = __builtin_amdgcn_mfma_f32_16x16x32_bf16(aF[m], bF[n], acc[m][n], 0,0,0);
    }
  }

  const int cr = (ln >> 4) * 4, ccol = ln & 15;
  #pragma unroll
  for (int m=0;m<4;m++){
    #pragma unroll
    for (int n=0;n<4;n++){
      int gc = ccol0 + wc*64 + n*16 + ccol;
      #pragma unroll
      for (int j=0;j<4;j++){
        int gr = row0 + wr*64 + m*16 + cr + j;
        float v = acc[m][n][j];
        if (AMODE == 0){
          Cf[(size_t)gr*ldcc + gc] = v;
        } else {
          if (act == 1) v = tanhf(v);
          else if (act == 2) v = 1.f/(1.f + expf(-v));
          Cbp[(size_t)gr*ldcc + gc] = f2bf(v);
        }
      }
    }
  }
}

// named wrappers
__global__ __launch_bounds__(256) void k_gemm_rkv(
  const u16* Abf, const float* xg, const float* shiftg, const float* ma, const float* mg,
  const u16* Bt, float* Cf, u16* Cb, int K, int lda, int ldb, int ldc, int nx)
{ gemm_body<2>(Abf, xg, shiftg, ma, mg, Bt, Cf, Cb, K, lda, ldb, ldc, nx); }

__global__ __launch_bounds__(256) void k_gemm_s2(
  const u16* Abf, const float* xg, const float* shiftg, const float* ma, const float* mg,
  const u16* Bt, float* Cf, u16* Cb, int K, int lda, int ldb, int ldc, int nx)
{ gemm_body<3>(Abf, xg, shiftg, ma, mg, Bt, Cf, Cb, K, lda, ldb, ldc, nx); }

__global__ __launch_bounds__(256) void k_gemm_fin(
  const u16* Abf, const float* xg, const float* shiftg, const float* ma, const float* mg,
  const u16* Bt, float* Cf, u16* Cb, int K, int lda, int ldb, int ldc, int nx)
{ gemm_body<0>(Abf, xg, shiftg, ma, mg, Bt, Cf, Cb, K, lda, ldb, ldc, nx); }

// ---------- post1 ----------
__global__ __launch_bounds__(256) void k_post1(
  u16* __restrict__ kb, u16* __restrict__ vb, const u16* __restrict__ winb,
  u16* __restrict__ ainb, u16* __restrict__ vinb,
  const float* __restrict__ vfirst,
  const float* __restrict__ w0, const float* __restrict__ a0, const float* __restrict__ v0,
  const float* __restrict__ kkv, const float* __restrict__ kav,
  float* __restrict__ dec)
{
  int grp = blockIdx.x*4 + (threadIdx.x >> 6);
  int n = threadIdx.x & 63;
  int i = grp >> 5, h = grp & 31;
  int c = h*64 + n;
  size_t idx = (size_t)i*CC + c;
  float k  = bf2f(kb[idx]),  v = bf2f(vb[idx]);
  float wi = bf2f(winb[idx]), ai = bf2f(ainb[idx]), vi = bf2f(vinb[idx]);
  float vf = vfirst[idx];
  float a  = 1.f/(1.f + expf(-(a0[c] + ai)));
  float z  = -(w0[c] + wi);
  float sp = (z > 15.f) ? z : log1pf(expf(z));
  float decay = expf(-expf(-sp - 0.5f));
  float vg = 1.f/(1.f + expf(-(v0[c] + vi)));
  float vfin = v + (vf - v)*vg;
  float kkr = k * kkv[c];
  float ss = wave_sum64(kkr*kkr);
  float kkn = kkr / fmaxf(sqrtf(ss), 1e-12f);
  float kfin = k * (1.f + (a - 1.f)*kav[c]);
  kb[idx] = f2bf(kfin);
  vb[idx] = f2bf(vfin);
  dec[idx] = decay;
  vinb[idx] = f2bf(kkn);
  ainb[idx] = f2bf(-(kkn * a));
}

// ---------- WKV scan v6 (measured best): asm-pinned prefetch, 2 x 8-step chunks ----------
#define SDECL(S) float4 w##S[8]; u32x2 b##S[8], k##S[8], kk##S[8], r##S[8]; u32 v##S[8];

#define SISSUE(S, t0) do {                                                        \
  _Pragma("unroll")                                                               \
  for (int s_=0; s_<8; ++s_){                                                     \
    u64 ow = (u64)(uintptr_t)&wb [gc0 + (size_t)((t0)+s_)*CC];                    \
    u64 ob = (u64)(uintptr_t)&bbp[gc0 + (size_t)((t0)+s_)*CC];                    \
    u64 ok = (u64)(uintptr_t)&kb [gc0 + (size_t)((t0)+s_)*CC];                    \
    u64 oq = (u64)(uintptr_t)&kkb[gc0 + (size_t)((t0)+s_)*CC];                    \
    u64 orr= (u64)(uintptr_t)&rb [gc0 + (size_t)((t0)+s_)*CC];                    \
    u64 ov = (u64)(uintptr_t)&vb [gv0 + (size_t)((t0)+s_)*CC];                    \
    asm volatile("global_load_dwordx4 %0, %1, off" : "=v"(w##S[s_])  : "v"(ow) : "memory"); \
    asm volatile("global_load_dwordx2 %0, %1, off" : "=v"(b##S[s_])  : "v"(ob) : "memory"); \
    asm volatile("global_load_dwordx2 %0, %1, off" : "=v"(k##S[s_])  : "v"(ok) : "memory"); \
    asm volatile("global_load_dwordx2 %0, %1, off" : "=v"(kk##S[s_]) : "v"(oq) : "memory"); \
    asm volatile("global_load_dwordx2 %0, %1, off" : "=v"(r##S[s_])  : "v"(orr): "memory"); \
    asm volatile("global_load_dword   %0, %1, off" : "=v"(v##S[s_])  : "v"(ov) : "memory"); \
  }                                                                               \
} while(0)

#define SCHUNK(S, t0, CNT) do {                                                   \
  asm volatile("s_waitcnt vmcnt(" #CNT ")" ::: "memory");                         \
  __builtin_amdgcn_sched_barrier(0);                                              \
  _Pragma("unroll")                                                               \
  for (int s_=0; s_<8; ++s_){                                                     \
    const float w_0=w##S[s_].x, w_1=w##S[s_].y, w_2=w##S[s_].z, w_3=w##S[s_].w;   \
    const float b_0=bflo(b##S[s_].x), b_1=bfhi(b##S[s_].x),                       \
                b_2=bflo(b##S[s_].y), b_3=bfhi(b##S[s_].y);                       \
    const float k_0=bflo(k##S[s_].x), k_1=bfhi(k##S[s_].x),                       \
                k_2=bflo(k##S[s_].y), k_3=bfhi(k##S[s_].y);                       \
    const float q_0=bflo(kk##S[s_].x), q_1=bfhi(kk##S[s_].x),                     \
                q_2=bflo(kk##S[s_].y), q_3=bfhi(kk##S[s_].y);                     \
    const float r_0=bflo(r##S[s_].x), r_1=bfhi(r##S[s_].x),                       \
                r_2=bflo(r##S[s_].y), r_3=bfhi(r##S[s_].y);                       \
    const float vv0_ = bflo(v##S[s_]);                                            \
    const float vv1_ = bfhi(v##S[s_]);                                            \
    float p0_ = fmaf(st[0][0],q_0, st[0][1]*q_1) + fmaf(st[0][2],q_2, st[0][3]*q_3); \
    float p1_ = fmaf(st[1][0],q_0, st[1][1]*q_1) + fmaf(st[1][2],q_2, st[1][3]*q_3); \
    p0_ = red16(p0_); p1_ = red16(p1_);                                           \
    st[0][0] = fmaf(st[0][0],w_0, fmaf(p0_,b_0, vv0_*k_0));                       \
    st[0][1] = fmaf(st[0][1],w_1, fmaf(p0_,b_1, vv0_*k_1));                       \
    st[0][2] = fmaf(st[0][2],w_2, fmaf(p0_,b_2, vv0_*k_2));                       \
    st[0][3] = fmaf(st[0][3],w_3, fmaf(p0_,b_3, vv0_*k_3));                       \
    st[1][0] = fmaf(st[1][0],w_0, fmaf(p1_,b_0, vv1_*k_0));                       \
    st[1][1] = fmaf(st[1][1],w_1, fmaf(p1_,b_1, vv1_*k_1));                       \
    st[1][2] = fmaf(st[1][2],w_2, fmaf(p1_,b_2, vv1_*k_2));                       \
    st[1][3] = fmaf(st[1][3],w_3, fmaf(p1_,b_3, vv1_*k_3));                       \
    float y0_ = fmaf(st[0][0],r_0, st[0][1]*r_1) + fmaf(st[0][2],r_2, st[0][3]*r_3); \
    float y1_ = fmaf(st[1][0],r_0, st[1][1]*r_1) + fmaf(st[1][2],r_2, st[1][3]*r_3); \
    y0_ = red16(y0_); y1_ = red16(y1_);                                           \
    if (cg == 0){                                                                 \
      u32 pk_ = (u32)f2bf(y0_) | ((u32)f2bf(y1_) << 16);                          \
      *(u32*)&yb[gv0 + (size_t)((t0)+s_)*CC] = pk_;                               \
    }                                                                             \
  }                                                                               \
} while(0)

__global__ __launch_bounds__(64, 1) void k_scan(
  const u16* __restrict__ rb, const float* __restrict__ wb,
  const u16* __restrict__ kb, const u16* __restrict__ vb,
  const u16* __restrict__ kkb, const u16* __restrict__ bbp,
  const float* __restrict__ wkv_in, u16* __restrict__ yb, float* __restrict__ wkv_out)
{
  const int blk = blockIdx.x;
  const int bh = blk & 127, oct = blk >> 7;
  const int b = bh >> 5, h = bh & 31;
  const int ln = threadIdx.x;
  const int rg = ln >> 4;
  const int cg = ln & 15;
  const int row0 = oct*8 + rg*2;
  const int col0 = cg*4;

  float st[2][4];
  {
    const float* sp0 = &wkv_in[((size_t)bh*64 + row0    )*64 + col0];
    const float* sp1 = &wkv_in[((size_t)bh*64 + row0 + 1)*64 + col0];
    float4 a = *(const float4*)sp0, c = *(const float4*)sp1;
    st[0][0]=a.x; st[0][1]=a.y; st[0][2]=a.z; st[0][3]=a.w;
    st[1][0]=c.x; st[1][1]=c.y; st[1][2]=c.z; st[1][3]=c.w;
  }

  const size_t gc0 = ((size_t)b*TT)*CC + h*64 + col0;
  const size_t gv0 = ((size_t)b*TT)*CC + h*64 + row0;

  SDECL(A) SDECL(B)

  SISSUE(A, 0);
  SISSUE(B, 8);
  SCHUNK(A, 0, 48);
  SISSUE(A, 16);
  SCHUNK(B, 8, 56);
  SISSUE(B, 24);
  for (int c = 1; c < 63; ++c){
    const int t0 = c*16;
    SCHUNK(A, t0, 56);
    SISSUE(A, t0+16);
    SCHUNK(B, t0+8, 56);
    SISSUE(B, t0+24);
  }
  SCHUNK(A, 1008, 56);
  SCHUNK(B, 1016, 0);

  {
    float* wo0 = &wkv_out[((size_t)bh*64 + row0    )*64 + col0];
    float* wo1 = &wkv_out[((size_t)bh*64 + row0 + 1)*64 + col0];
    *(float4*)wo0 = make_float4(st[0][0], st[0][1], st[0][2], st[0][3]);
    *(float4*)wo1 = make_float4(st[1][0], st[1][1], st[1][2], st[1][3]);
  }
}

// ---------- post2 ----------
__global__ __launch_bounds__(256) void k_post2(
  const u16* __restrict__ ybuf, const u16* __restrict__ rbuf,
  const u16* __restrict__ kfb, const u16* __restrict__ vfb,
  const u16* __restrict__ gbuf, const float* __restrict__ rk,
  const float* __restrict__ lnw, const float* __restrict__ lnb, u16* __restrict__ ao)
{
  int grp = blockIdx.x*4 + (threadIdx.x >> 6);
  int n = threadIdx.x & 63;
  int i = grp >> 5, h = grp & 31;
  int c = h*64 + n;
  size_t idx = (size_t)i*CC + c;
  float y = bf2f(ybuf[idx]);
  float s1 = wave_sum64(y);
  float s2 = wave_sum64(y*y);
  float mu = s1 * (1.f/64.f);
  float var = s2 * (1.f/64.f) - mu*mu;
  float yn = (y - mu) * rsqrtf(var + 6.4e-4f) * lnw[c] + lnb[c];
  float rv = bf2f(rbuf[idx]), kv = bf2f(kfb[idx]);
  float s3 = wave_sum64(rv * kv * rk[c]);
  float bonus = s3 * bf2f(vfb[idx]);
  ao[idx] = f2bf((yn + bonus) * bf2f(gbuf[idx]));
}

// ---------- shift_state_out = x[:, -1] (runs LAST; d_out scratch dead by then) ----------
__global__ __launch_bounds__(256) void k_shift(const float* __restrict__ x, float* __restrict__ so){
  int i = blockIdx.x*256 + threadIdx.x;
  int b = i >> 9, c4 = (i & 511)*4;
  *(float4*)&so[(size_t)b*CC + c4] = *(const float4*)&x[((size_t)(b*TT + TT-1))*CC + c4];
}

// ---------- launch ----------
extern "C" void kernel_launch(void* const* d_in, const int* in_sizes, int n_in,
                              void* d_out, int out_size, void* d_ws, size_t ws_size,
                              hipStream_t stream)
{
  const float* x        = (const float*)d_in[0];
  const float* shift_in = (const float*)d_in[1];
  const float* wkv_in   = (const float*)d_in[2];
  const float* v_first  = (const float*)d_in[3];
  const float* x_r = (const float*)d_in[4];
  const float* x_w = (const float*)d_in[5];
  const float* x_k = (const float*)d_in[6];
  const float* x_v = (const float*)d_in[7];
  const float* x_a = (const float*)d_in[8];
  const float* x_g = (const float*)d_in[9];
  const float* w0 = (const float*)d_in[10];
  const float* w1 = (const float*)d_in[11];
  const float* w2 = (const float*)d_in[12];
  const float* a0 = (const float*)d_in[13];
  const float* a1 = (const float*)d_in[14];
  const float* a2 = (const float*)d_in[15];
  const float* v0 = (const float*)d_in[16];
  const float* v1 = (const float*)d_in[17];
  const float* v2 = (const float*)d_in[18];
  const float* g1 = (const float*)d_in[19];
  const float* g2 = (const float*)d_in[20];
  const float* k_k = (const float*)d_in[21];
  const float* k_a = (const float*)d_in[22];
  const float* r_k = (const float*)d_in[23];
  const float* Wr = (const float*)d_in[24];
  const float* Wk = (const float*)d_in[25];
  const float* Wv = (const float*)d_in[26];
  const float* Wo = (const float*)d_in[27];
  const float* ln_w = (const float*)d_in[28];
  const float* ln_b = (const float*)d_in[29];

  // ---- ws layout ----
  char* ws = (char*)d_ws;
  u16* WOB  = (u16*)(ws + 0);
  u16* WRB  = (u16*)(ws + 8388608);
  u16* B2W  = (u16*)(ws + 36175872);
  u16* PBUF = (u16*)(ws + 38797312);
  u16* RB   = (u16*)(ws + 44040192);
  u16* KB   = (u16*)(ws + 60817408);
  u16* VB   = (u16*)(ws + 77594624);
  u16* YB   = (u16*)(ws + 94371840);
  float* DEC  = (float*)(ws + 8388608);
  u16* AO   = (u16*)(ws + 8388608);

  // ---- d_out scratch ----
  float* out       = (float*)d_out;
  float* shift_out = out + 8388608;
  float* wkv_out   = out + 8396800;
  float* vf_out    = out + 8921088;
  u16* XRKV = (u16*)d_out;
  u16* WINb = (u16*)d_out;
  u16* AINb = (u16*)((char*)d_out + 16777216);
  u16* VINb = (u16*)((char*)d_out + 35684352);

  // merged weight prep (casts + transposes, one launch)
  k_wprep<<<18944, 256, 0, stream>>>(Wr, Wk, Wv, Wo, w1, a1, v1, g1, w2, a2, v2, g2, (u16*)ws);

  // token-shift mix precompute
  k_prep4<<<8192, 256, 0, stream>>>(x, shift_in, x_r, x_k, x_v, x_w,
                                    XRKV, XRKV + 8388608u, XRKV + 16777216u, XRKV + 25165824u);

  // fused r/k/v + stage-1 GEMM (1D grid, XCD-chunked swizzle, BK=64)
  k_gemm_rkv<<<1696, 256, 0, stream>>>(XRKV, x, shift_in, x_a, x_g,
                                       WRB, (float*)PBUF, RB, 2048, 2048, 2048, 2048, 53);

  // fused stage-2 GEMMs
  k_gemm_s2<<<2048, 256, 0, stream>>>(PBUF, nullptr, nullptr, nullptr, nullptr,
                                      B2W, nullptr, (u16*)d_out, 0, 640, 128, 2048, 64);

  // elementwise post
  k_post1<<<32768, 256, 0, stream>>>(KB, VB, WINb, AINb, VINb, v_first,
                                     w0, a0, v0, k_k, k_a, DEC);

  // sequential WKV scan (v6: asm-pinned prefetch, counted vmcnt)
  k_scan<<<1024, 64, 0, stream>>>(RB, DEC, KB, VB, VINb, AINb, wkv_in, YB, wkv_out);

  // groupnorm + bonus + gate
  k_post2<<<32768, 256, 0, stream>>>(YB, RB, KB, VB, (u16*)((char*)d_out + 52461568),
                                     r_k, ln_w, ln_b, AO);

  // final GEMM -> out
  k_gemm_fin<<<512, 256, 0, stream>>>(AO, nullptr, nullptr, nullptr, nullptr,
                                      WOB, out, nullptr, 2048, 2048, 2048, 2048, 16);

  // small outputs last (XV dead; shift_out region safe now)
  k_shift<<<8, 256, 0, stream>>>(x, shift_out);
  hipMemcpyAsync(vf_out, v_first, 33554432, hipMemcpyDeviceToDevice, stream);
}

// Round 17
// 663.379 us; speedup vs baseline: 1.1159x; 1.0047x over previous
//
#include <hip/hip_runtime.h>
#include <hip/hip_bf16.h>
#include <stdint.h>

typedef unsigned short u16;
typedef unsigned int u32;
typedef unsigned long long u64;
typedef __attribute__((ext_vector_type(8))) short short8;
typedef __attribute__((ext_vector_type(4))) float f32x4;
typedef __attribute__((ext_vector_type(2))) unsigned int u32x2;

#define BB 4
#define TT 1024
#define CC 2048

// ---------- helpers ----------
__device__ __forceinline__ u16 f2bf(float f){
  __hip_bfloat16 h = __float2bfloat16(f);
  return *reinterpret_cast<u16*>(&h);
}
__device__ __forceinline__ float bf2f(u16 h){
  union { u32 u; float f; } v; v.u = ((u32)h) << 16; return v.f;
}
__device__ __forceinline__ float bflo(u32 p){
  union { u32 u; float f; } v; v.u = p << 16; return v.f;
}
__device__ __forceinline__ float bfhi(u32 p){
  union { u32 u; float f; } v; v.u = p & 0xFFFF0000u; return v.f;
}

__device__ __forceinline__ void gload16(const void* g, void* s){
  __builtin_amdgcn_global_load_lds((const __attribute__((address_space(1))) u32*)g,
                                   (__attribute__((address_space(3))) u32*)s, 16, 0, 0);
}

__device__ __forceinline__ float wave_sum64(float x){
  #pragma unroll
  for (int m = 1; m < 64; m <<= 1) x += __shfl_xor(x, m, 64);
  return x;
}

template<int N>
__device__ __forceinline__ float ror_add(float x){
  int t = __builtin_amdgcn_update_dpp(0, __builtin_bit_cast(int, x), 0x120 | N, 0xF, 0xF, false);
  return x + __builtin_bit_cast(float, t);
}
__device__ __forceinline__ float red16(float x){
  x = ror_add<8>(x); x = ror_add<4>(x); x = ror_add<2>(x); x = ror_add<1>(x);
  return x;
}

// Bijective XCD-chunked swizzle (m204), bx-major within an A-row-panel.
__device__ __forceinline__ void xcd_map(int nx, int& bx, int& row0){
  const int G = gridDim.x;
  const int q = G >> 3, r = G & 7;
  const int xcd = blockIdx.x & 7, i2 = blockIdx.x >> 3;
  const int sw = (xcd < r) ? (xcd*(q+1) + i2) : (r*(q+1) + (xcd - r)*q + i2);
  const int by = sw / nx;
  bx = sw - by*nx;
  row0 = by * 128;
}

// ---------- merged weight prep: casts (blk<16384) + tiled transposes (blk>=16384) ----------
__global__ __launch_bounds__(256) void k_wprep(
  const float* __restrict__ wr, const float* __restrict__ wk,
  const float* __restrict__ wv, const float* __restrict__ wo,
  const float* __restrict__ w1, const float* __restrict__ a1,
  const float* __restrict__ v1, const float* __restrict__ g1,
  const float* __restrict__ w2, const float* __restrict__ a2,
  const float* __restrict__ v2, const float* __restrict__ g2,
  u16* __restrict__ wsb)
{
  __shared__ float lds[32][33];
  const int blk0 = blockIdx.x;
  if (blk0 < 16384){
    int i = blk0*256 + threadIdx.x;
    int seg = i >> 20;
    int off = (i & 1048575) * 4;
    const float* src = (seg==0) ? wr : (seg==1) ? wk : (seg==2) ? wv : wo;
    const size_t dofs = (seg==0) ? 4194304u : (seg==1) ? 8388608u : (seg==2) ? 12582912u : 0u;
    float4 v = *(const float4*)&src[off];
    *(ushort4*)&wsb[dofs + off] = make_ushort4(f2bf(v.x), f2bf(v.y), f2bf(v.z), f2bf(v.w));
    return;
  }
  const int blk = blk0 - 16384;
  const float* src; int R, S, Rpad, tile, tiles_r; size_t dst;
  if      (blk <  256){ src=w1; R=2048; S=96;   Rpad=2048; dst=16777216u; tile=blk;      tiles_r=64; }
  else if (blk <  512){ src=a1; R=2048; S=96;   Rpad=2048; dst=17039360u; tile=blk-256;  tiles_r=64; }
  else if (blk <  768){ src=v1; R=2048; S=64;   Rpad=2048; dst=17301504u; tile=blk-512;  tiles_r=64; }
  else if (blk < 1280){ src=g1; R=2048; S=256;  Rpad=2048; dst=17563648u; tile=blk-768;  tiles_r=64; }
  else if (blk < 1536){ src=w2; R=96;   S=2048; Rpad=128;  dst=18087936u; tile=blk-1280; tiles_r=4;  }
  else if (blk < 1792){ src=a2; R=96;   S=2048; Rpad=128;  dst=18350080u; tile=blk-1536; tiles_r=4;  }
  else if (blk < 2048){ src=v2; R=64;   S=2048; Rpad=128;  dst=18612224u; tile=blk-1792; tiles_r=4;  }
  else                { src=g2; R=256;  S=2048; Rpad=256;  dst=18874368u; tile=blk-2048; tiles_r=8;  }
  const int tr = tile % tiles_r, ts = tile / tiles_r;
  const int r0 = tr*32, s0 = ts*32;
  const int tj = threadIdx.x & 31, ti = threadIdx.x >> 5;
  #pragma unroll
  for (int p=0;p<4;p++){
    int rr = r0 + p*8 + ti, ss = s0 + tj;
    lds[p*8+ti][tj] = (rr < R && ss < S) ? src[(size_t)rr*S + ss] : 0.f;
  }
  __syncthreads();
  #pragma unroll
  for (int p=0;p<4;p++){
    int sl = p*8 + ti, rl = tj;
    wsb[dst + (size_t)(s0+sl)*Rpad + r0 + rl] = f2bf(lds[rl][sl]);
  }
}

// ---------- prep: token-shift mix -> XR,XK,XV,XW bf16 ----------
__global__ __launch_bounds__(256) void k_prep4(
  const float* __restrict__ x, const float* __restrict__ shift_in,
  const float* __restrict__ mr, const float* __restrict__ mk,
  const float* __restrict__ mv, const float* __restrict__ mw,
  u16* __restrict__ xr, u16* __restrict__ xk, u16* __restrict__ xv, u16* __restrict__ xw)
{
  int idx = blockIdx.x*256 + threadIdx.x;
  int c4 = (idx & 511) * 4;
  int t  = (idx >> 9) & (TT-1);
  int b  = idx >> 19;
  size_t xo = ((size_t)(b*TT + t))*CC + c4;
  float4 xc = *(const float4*)&x[xo];
  float4 xp = (t == 0) ? *(const float4*)&shift_in[(size_t)b*CC + c4]
                       : *(const float4*)&x[xo - CC];
  float d0 = xp.x-xc.x, d1 = xp.y-xc.y, d2 = xp.z-xc.z, d3 = xp.w-xc.w;
#define MIXO(mp, op) { float4 m = *(const float4*)&mp[c4]; \
    *(ushort4*)&op[xo] = make_ushort4(f2bf(fmaf(d0,m.x,xc.x)), f2bf(fmaf(d1,m.y,xc.y)), \
                                      f2bf(fmaf(d2,m.z,xc.z)), f2bf(fmaf(d3,m.w,xc.w))); }
  MIXO(mr, xr); MIXO(mk, xk); MIXO(mv, xv); MIXO(mw, xw);
#undef MIXO
}

// ---------- GEMM body: 128x128 tile, BK=64, both-sides swizzle, XCD-chunked.
// Non-bmix path: DOUBLE-BUFFERED counted-vmcnt pipeline (T3-minimum):
//   stage(buf0); loop{ stage(buf^1); vmcnt(8); barrier; compute(buf); barrier; }
// bmix path (3 blocks): legacy serial flow with __syncthreads.
template<int AMODE>
__device__ __forceinline__ void gemm_body(
  const u16* __restrict__ Abf,
  const float* __restrict__ xg, const float* __restrict__ shiftg,
  const float* __restrict__ ma, const float* __restrict__ mg,
  const u16* __restrict__ Bt, float* __restrict__ Cf, u16* __restrict__ Cb,
  int K, int lda, int ldb, int ldc, int nx)
{
  __shared__ alignas(16) u16 sA[2*128*64];
  __shared__ alignas(16) u16 sB[2*128*64];
  const int tid = threadIdx.x;
  const int wv = tid >> 6, ln = tid & 63;
  int bx, row0;
  xcd_map(nx, bx, row0);
  const int wr = wv >> 1, wc = wv & 1;

  const float* mixv = nullptr;
  const u16* Ap = Abf;
  const u16* Btp = Bt;
  u16* Cbp = Cb;
  bool bmix = false;
  int bcol0 = bx * 128;
  int ccol0 = bx * 128;
  int ldaa = lda, ldbb = ldb, ldcc = ldc;
  int KK = K, act = 0;

  if (AMODE == 2){
    if (bx < 48){
      int sel = bx >> 4;
      Ap = Abf + (size_t)sel * 8388608u;
      Cbp = Cb + (size_t)sel * 8388608u;
      ccol0 = (bx & 15) * 128;
      ldcc = 2048; ldaa = 2048;
    } else {
      int sb = bx - 48;
      Cbp = (u16*)Cf;
      ccol0 = sb * 128;
      ldcc = 640;
      act = (sb==0) ? 1 : (sb>=3 ? 2 : 0);
      if (sb == 0){ Ap = Abf + 25165824u; ldaa = 2048; }
      else if (sb == 2){ Ap = Abf + 16777216u; ldaa = 2048; }
      else { bmix = true; mixv = (sb==1) ? ma : mg; }
    }
  }
  if (AMODE == 3){
    int sel = bx >> 4;
    Ap = Abf + sel*128;
    Btp = Bt + (size_t)sel * 262144u;
    ldbb = (sel==3) ? 256 : 128;
    KK = (sel==3) ? 256 : 128;
    const int coffs[4] = {0, 8388608, 17842176, 26230784};
    Cbp = Cb + coffs[sel];
    ccol0 = (bx & 15) * 128;
    bcol0 = ccol0;
    ldcc = 2048;
  }

  f32x4 acc[4][4] = {};
  const int srow = ln >> 3;
  const int scol = ((ln & 7) ^ srow) * 8;       // pre-swizzled global col (elems)
  const int ob0  = wv * 4096;                   // wave LDS byte base within a buffer
  const int rsw  = (ln & 7) << 3;               // read-side XOR (elems)

  if (AMODE != 2 || !bmix){
    // ---- pipelined path ----
    const int NT = KK >> 6;
    auto STAGE = [&](int q, int k0){
      #pragma unroll
      for (int j=0;j<4;j++)
        gload16(&Ap[(size_t)(row0 + wv*32 + j*8 + srow)*ldaa + k0 + scol],
                (void*)((char*)sA + q*16384 + ob0 + j*1024));
      #pragma unroll
      for (int j=0;j<4;j++)
        gload16(&Btp[(size_t)(bcol0 + wv*32 + j*8 + srow)*ldbb + k0 + scol],
                (void*)((char*)sB + q*16384 + ob0 + j*1024));
    };
    STAGE(0, 0);
    for (int t = 0; t < NT; ++t){
      const int cur = t & 1;
      if (t+1 < NT){
        STAGE(cur^1, (t+1) << 6);
        asm volatile("s_waitcnt vmcnt(8)" ::: "memory");
      } else {
        asm volatile("s_waitcnt vmcnt(0)" ::: "memory");
      }
      __builtin_amdgcn_s_barrier();
      __builtin_amdgcn_sched_barrier(0);
      const u16* sAq = sA + cur*8192;
      const u16* sBq = sB + cur*8192;
      #pragma unroll
      for (int kk = 0; kk < 2; ++kk){
        short8 aF[4], bF[4];
        #pragma unroll
        for (int m=0;m<4;m++){
          int rr = wr*64 + m*16 + (ln&15);
          aF[m] = *(const short8*)&sAq[rr*64 + ((kk*32 + (ln>>4)*8) ^ rsw)];
        }
        #pragma unroll
        for (int n=0;n<4;n++){
          int rr = wc*64 + n*16 + (ln&15);
          bF[n] = *(const short8*)&sBq[rr*64 + ((kk*32 + (ln>>4)*8) ^ rsw)];
        }
        #pragma unroll
        for (int m=0;m<4;m++)
          #pragma unroll
          for (int n=0;n<4;n++)
            acc[m][n] = __builtin_amdgcn_mfma_f32_16x16x32_bf16(aF[m], bF[n], acc[m][n], 0,0,0);
      }
      __builtin_amdgcn_s_barrier();
      __builtin_amdgcn_sched_barrier(0);
    }
  } else {
    // ---- legacy serial path (bmix: on-the-fly mix, buffer 0 only) ----
    for (int k0 = 0; k0 < KK; k0 += 64){
      __syncthreads();
      #pragma unroll
      for (int j=0;j<4;j++)
        gload16(&Btp[(size_t)(bcol0 + wv*32 + j*8 + srow)*ldbb + k0 + scol],
                (void*)((char*)sB + ob0 + j*1024));
      const int r_  = tid >> 2;
      const int akc = (tid & 3) * 8;
      #pragma unroll
      for (int kb2 = 0; kb2 < 64; kb2 += 32){
        float4 m0 = *(const float4*)&mixv[k0 + kb2 + akc];
        float4 m1 = *(const float4*)&mixv[k0 + kb2 + akc + 4];
        #pragma unroll
        for (int it = 0; it < 2; ++it){
          int r = r_ + it*64;
          int gr = row0 + r;
          size_t xo = (size_t)gr*CC + k0 + kb2 + akc;
          float4 c0 = *(const float4*)&xg[xo];
          float4 c1 = *(const float4*)&xg[xo + 4];
          const float* pp = ((gr & (TT-1)) == 0) ? &shiftg[(size_t)(gr >> 10)*CC + k0 + kb2 + akc]
                                                 : &xg[xo - CC];
          float4 p0 = *(const float4*)&pp[0];
          float4 p1 = *(const float4*)&pp[4];
          short8 vvv;
          vvv[0] = (short)f2bf(c0.x + (p0.x - c0.x)*m0.x);
          vvv[1] = (short)f2bf(c0.y + (p0.y - c0.y)*m0.y);
          vvv[2] = (short)f2bf(c0.z + (p0.z - c0.z)*m0.z);
          vvv[3] = (short)f2bf(c0.w + (p0.w - c0.w)*m0.w);
          vvv[4] = (short)f2bf(c1.x + (p1.x - c1.x)*m1.x);
          vvv[5] = (short)f2bf(c1.y + (p1.y - c1.y)*m1.y);
          vvv[6] = (short)f2bf(c1.z + (p1.z - c1.z)*m1.z);
          vvv[7] = (short)f2bf(c1.w + (p1.w - c1.w)*m1.w);
          int csw = (kb2 + akc) ^ ((r & 7) << 3);
          *(short8*)&sA[r*64 + csw] = vvv;
        }
      }
      __syncthreads();
      #pragma unroll
      for (int kk = 0; kk < 2; ++kk){
        short8 aF[4], bF[4];
        #pragma unroll
        for (int m=0;m<4;m++){
          int rr = wr*64 + m*16 + (ln&15);
          aF[m] = *(const short8*)&sA[rr*64 + ((kk*32 + (ln>>4)*8) ^ rsw)];
        }
        #pragma unroll
        for (int n=0;n<4;n++){
          int rr = wc*64 + n*16 + (ln&15);
          bF[n] = *(const short8*)&sB[rr*64 + ((kk*32 + (ln>>4)*8) ^ rsw)];
        }
        #pragma unroll
        for (int m=0;m<4;m++)
          #pragma unroll
          for (int n=0;n<4;n++)
            acc[m][n] = __builtin_amdgcn_mfma_f32_16x16x32_bf16(aF[m], bF[n], acc[m][n], 0,0,0);
      }
    }
  }

  const int cr = (ln >> 4) * 4, ccol = ln & 15;
  #pragma unroll
  for (int m=0;m<4;m++){
    #pragma unroll
    for (int n=0;n<4;n++){
      int gc = ccol0 + wc*64 + n*16 + ccol;
      #pragma unroll
      for (int j=0;j<4;j++){
        int gr = row0 + wr*64 + m*16 + cr + j;
        float v = acc[m][n][j];
        if (AMODE == 0){
          Cf[(size_t)gr*ldcc + gc] = v;
        } else {
          if (act == 1) v = tanhf(v);
          else if (act == 2) v = 1.f/(1.f + expf(-v));
          Cbp[(size_t)gr*ldcc + gc] = f2bf(v);
        }
      }
    }
  }
}

// named wrappers
__global__ __launch_bounds__(256) void k_gemm_rkv(
  const u16* Abf, const float* xg, const float* shiftg, const float* ma, const float* mg,
  const u16* Bt, float* Cf, u16* Cb, int K, int lda, int ldb, int ldc, int nx)
{ gemm_body<2>(Abf, xg, shiftg, ma, mg, Bt, Cf, Cb, K, lda, ldb, ldc, nx); }

__global__ __launch_bounds__(256) void k_gemm_s2(
  const u16* Abf, const float* xg, const float* shiftg, const float* ma, const float* mg,
  const u16* Bt, float* Cf, u16* Cb, int K, int lda, int ldb, int ldc, int nx)
{ gemm_body<3>(Abf, xg, shiftg, ma, mg, Bt, Cf, Cb, K, lda, ldb, ldc, nx); }

__global__ __launch_bounds__(256) void k_gemm_fin(
  const u16* Abf, const float* xg, const float* shiftg, const float* ma, const float* mg,
  const u16* Bt, float* Cf, u16* Cb, int K, int lda, int ldb, int ldc, int nx)
{ gemm_body<0>(Abf, xg, shiftg, ma, mg, Bt, Cf, Cb, K, lda, ldb, ldc, nx); }

// ---------- post1 ----------
__global__ __launch_bounds__(256) void k_post1(
  u16* __restrict__ kb, u16* __restrict__ vb, const u16* __restrict__ winb,
  u16* __restrict__ ainb, u16* __restrict__ vinb,
  const float* __restrict__ vfirst,
  const float* __restrict__ w0, const float* __restrict__ a0, const float* __restrict__ v0,
  const float* __restrict__ kkv, const float* __restrict__ kav,
  float* __restrict__ dec)
{
  int grp = blockIdx.x*4 + (threadIdx.x >> 6);
  int n = threadIdx.x & 63;
  int i = grp >> 5, h = grp & 31;
  int c = h*64 + n;
  size_t idx = (size_t)i*CC + c;
  float k  = bf2f(kb[idx]),  v = bf2f(vb[idx]);
  float wi = bf2f(winb[idx]), ai = bf2f(ainb[idx]), vi = bf2f(vinb[idx]);
  float vf = vfirst[idx];
  float a  = 1.f/(1.f + expf(-(a0[c] + ai)));
  float z  = -(w0[c] + wi);
  float sp = (z > 15.f) ? z : log1pf(expf(z));
  float decay = expf(-expf(-sp - 0.5f));
  float vg = 1.f/(1.f + expf(-(v0[c] + vi)));
  float vfin = v + (vf - v)*vg;
  float kkr = k * kkv[c];
  float ss = wave_sum64(kkr*kkr);
  float kkn = kkr / fmaxf(sqrtf(ss), 1e-12f);
  float kfin = k * (1.f + (a - 1.f)*kav[c]);
  kb[idx] = f2bf(kfin);
  vb[idx] = f2bf(vfin);
  dec[idx] = decay;
  vinb[idx] = f2bf(kkn);
  ainb[idx] = f2bf(-(kkn * a));
}

// ---------- WKV scan v6 (measured best): asm-pinned prefetch, 2 x 8-step chunks ----------
#define SDECL(S) float4 w##S[8]; u32x2 b##S[8], k##S[8], kk##S[8], r##S[8]; u32 v##S[8];

#define SISSUE(S, t0) do {                                                        \
  _Pragma("unroll")                                                               \
  for (int s_=0; s_<8; ++s_){                                                     \
    u64 ow = (u64)(uintptr_t)&wb [gc0 + (size_t)((t0)+s_)*CC];                    \
    u64 ob = (u64)(uintptr_t)&bbp[gc0 + (size_t)((t0)+s_)*CC];                    \
    u64 ok = (u64)(uintptr_t)&kb [gc0 + (size_t)((t0)+s_)*CC];                    \
    u64 oq = (u64)(uintptr_t)&kkb[gc0 + (size_t)((t0)+s_)*CC];                    \
    u64 orr= (u64)(uintptr_t)&rb [gc0 + (size_t)((t0)+s_)*CC];                    \
    u64 ov = (u64)(uintptr_t)&vb [gv0 + (size_t)((t0)+s_)*CC];                    \
    asm volatile("global_load_dwordx4 %0, %1, off" : "=v"(w##S[s_])  : "v"(ow) : "memory"); \
    asm volatile("global_load_dwordx2 %0, %1, off" : "=v"(b##S[s_])  : "v"(ob) : "memory"); \
    asm volatile("global_load_dwordx2 %0, %1, off" : "=v"(k##S[s_])  : "v"(ok) : "memory"); \
    asm volatile("global_load_dwordx2 %0, %1, off" : "=v"(kk##S[s_]) : "v"(oq) : "memory"); \
    asm volatile("global_load_dwordx2 %0, %1, off" : "=v"(r##S[s_])  : "v"(orr): "memory"); \
    asm volatile("global_load_dword   %0, %1, off" : "=v"(v##S[s_])  : "v"(ov) : "memory"); \
  }                                                                               \
} while(0)

#define SCHUNK(S, t0, CNT) do {                                                   \
  asm volatile("s_waitcnt vmcnt(" #CNT ")" ::: "memory");                         \
  __builtin_amdgcn_sched_barrier(0);                                              \
  _Pragma("unroll")                                                               \
  for (int s_=0; s_<8; ++s_){                                                     \
    const float w_0=w##S[s_].x, w_1=w##S[s_].y, w_2=w##S[s_].z, w_3=w##S[s_].w;   \
    const float b_0=bflo(b##S[s_].x), b_1=bfhi(b##S[s_].x),                       \
                b_2=bflo(b##S[s_].y), b_3=bfhi(b##S[s_].y);                       \
    const float k_0=bflo(k##S[s_].x), k_1=bfhi(k##S[s_].x),                       \
                k_2=bflo(k##S[s_].y), k_3=bfhi(k##S[s_].y);                       \
    const float q_0=bflo(kk##S[s_].x), q_1=bfhi(kk##S[s_].x),                     \
                q_2=bflo(kk##S[s_].y), q_3=bfhi(kk##S[s_].y);                     \
    const float r_0=bflo(r##S[s_].x), r_1=bfhi(r##S[s_].x),                       \
                r_2=bflo(r##S[s_].y), r_3=bfhi(r##S[s_].y);                       \
    const float vv0_ = bflo(v##S[s_]);                                            \
    const float vv1_ = bfhi(v##S[s_]);                                            \
    float p0_ = fmaf(st[0][0],q_0, st[0][1]*q_1) + fmaf(st[0][2],q_2, st[0][3]*q_3); \
    float p1_ = fmaf(st[1][0],q_0, st[1][1]*q_1) + fmaf(st[1][2],q_2, st[1][3]*q_3); \
    p0_ = red16(p0_); p1_ = red16(p1_);                                           \
    st[0][0] = fmaf(st[0][0],w_0, fmaf(p0_,b_0, vv0_*k_0));                       \
    st[0][1] = fmaf(st[0][1],w_1, fmaf(p0_,b_1, vv0_*k_1));                       \
    st[0][2] = fmaf(st[0][2],w_2, fmaf(p0_,b_2, vv0_*k_2));                       \
    st[0][3] = fmaf(st[0][3],w_3, fmaf(p0_,b_3, vv0_*k_3));                       \
    st[1][0] = fmaf(st[1][0],w_0, fmaf(p1_,b_0, vv1_*k_0));                       \
    st[1][1] = fmaf(st[1][1],w_1, fmaf(p1_,b_1, vv1_*k_1));                       \
    st[1][2] = fmaf(st[1][2],w_2, fmaf(p1_,b_2, vv1_*k_2));                       \
    st[1][3] = fmaf(st[1][3],w_3, fmaf(p1_,b_3, vv1_*k_3));                       \
    float y0_ = fmaf(st[0][0],r_0, st[0][1]*r_1) + fmaf(st[0][2],r_2, st[0][3]*r_3); \
    float y1_ = fmaf(st[1][0],r_0, st[1][1]*r_1) + fmaf(st[1][2],r_2, st[1][3]*r_3); \
    y0_ = red16(y0_); y1_ = red16(y1_);                                           \
    if (cg == 0){                                                                 \
      u32 pk_ = (u32)f2bf(y0_) | ((u32)f2bf(y1_) << 16);                          \
      *(u32*)&yb[gv0 + (size_t)((t0)+s_)*CC] = pk_;                               \
    }                                                                             \
  }                                                                               \
} while(0)

__global__ __launch_bounds__(64, 1) void k_scan(
  const u16* __restrict__ rb, const float* __restrict__ wb,
  const u16* __restrict__ kb, const u16* __restrict__ vb,
  const u16* __restrict__ kkb, const u16* __restrict__ bbp,
  const float* __restrict__ wkv_in, u16* __restrict__ yb, float* __restrict__ wkv_out)
{
  const int blk = blockIdx.x;
  const int bh = blk & 127, oct = blk >> 7;
  const int b = bh >> 5, h = bh & 31;
  const int ln = threadIdx.x;
  const int rg = ln >> 4;
  const int cg = ln & 15;
  const int row0 = oct*8 + rg*2;
  const int col0 = cg*4;

  float st[2][4];
  {
    const float* sp0 = &wkv_in[((size_t)bh*64 + row0    )*64 + col0];
    const float* sp1 = &wkv_in[((size_t)bh*64 + row0 + 1)*64 + col0];
    float4 a = *(const float4*)sp0, c = *(const float4*)sp1;
    st[0][0]=a.x; st[0][1]=a.y; st[0][2]=a.z; st[0][3]=a.w;
    st[1][0]=c.x; st[1][1]=c.y; st[1][2]=c.z; st[1][3]=c.w;
  }

  const size_t gc0 = ((size_t)b*TT)*CC + h*64 + col0;
  const size_t gv0 = ((size_t)b*TT)*CC + h*64 + row0;

  SDECL(A) SDECL(B)

  SISSUE(A, 0);
  SISSUE(B, 8);
  SCHUNK(A, 0, 48);
  SISSUE(A, 16);
  SCHUNK(B, 8, 56);
  SISSUE(B, 24);
  for (int c = 1; c < 63; ++c){
    const int t0 = c*16;
    SCHUNK(A, t0, 56);
    SISSUE(A, t0+16);
    SCHUNK(B, t0+8, 56);
    SISSUE(B, t0+24);
  }
  SCHUNK(A, 1008, 56);
  SCHUNK(B, 1016, 0);

  {
    float* wo0 = &wkv_out[((size_t)bh*64 + row0    )*64 + col0];
    float* wo1 = &wkv_out[((size_t)bh*64 + row0 + 1)*64 + col0];
    *(float4*)wo0 = make_float4(st[0][0], st[0][1], st[0][2], st[0][3]);
    *(float4*)wo1 = make_float4(st[1][0], st[1][1], st[1][2], st[1][3]);
  }
}

// ---------- post2 ----------
__global__ __launch_bounds__(256) void k_post2(
  const u16* __restrict__ ybuf, const u16* __restrict__ rbuf,
  const u16* __restrict__ kfb, const u16* __restrict__ vfb,
  const u16* __restrict__ gbuf, const float* __restrict__ rk,
  const float* __restrict__ lnw, const float* __restrict__ lnb, u16* __restrict__ ao)
{
  int grp = blockIdx.x*4 + (threadIdx.x >> 6);
  int n = threadIdx.x & 63;
  int i = grp >> 5, h = grp & 31;
  int c = h*64 + n;
  size_t idx = (size_t)i*CC + c;
  float y = bf2f(ybuf[idx]);
  float s1 = wave_sum64(y);
  float s2 = wave_sum64(y*y);
  float mu = s1 * (1.f/64.f);
  float var = s2 * (1.f/64.f) - mu*mu;
  float yn = (y - mu) * rsqrtf(var + 6.4e-4f) * lnw[c] + lnb[c];
  float rv = bf2f(rbuf[idx]), kv = bf2f(kfb[idx]);
  float s3 = wave_sum64(rv * kv * rk[c]);
  float bonus = s3 * bf2f(vfb[idx]);
  ao[idx] = f2bf((yn + bonus) * bf2f(gbuf[idx]));
}

// ---------- shift_state_out = x[:, -1] (runs LAST; d_out scratch dead by then) ----------
__global__ __launch_bounds__(256) void k_shift(const float* __restrict__ x, float* __restrict__ so){
  int i = blockIdx.x*256 + threadIdx.x;
  int b = i >> 9, c4 = (i & 511)*4;
  *(float4*)&so[(size_t)b*CC + c4] = *(const float4*)&x[((size_t)(b*TT + TT-1))*CC + c4];
}

// ---------- launch ----------
extern "C" void kernel_launch(void* const* d_in, const int* in_sizes, int n_in,
                              void* d_out, int out_size, void* d_ws, size_t ws_size,
                              hipStream_t stream)
{
  const float* x        = (const float*)d_in[0];
  const float* shift_in = (const float*)d_in[1];
  const float* wkv_in   = (const float*)d_in[2];
  const float* v_first  = (const float*)d_in[3];
  const float* x_r = (const float*)d_in[4];
  const float* x_w = (const float*)d_in[5];
  const float* x_k = (const float*)d_in[6];
  const float* x_v = (const float*)d_in[7];
  const float* x_a = (const float*)d_in[8];
  const float* x_g = (const float*)d_in[9];
  const float* w0 = (const float*)d_in[10];
  const float* w1 = (const float*)d_in[11];
  const float* w2 = (const float*)d_in[12];
  const float* a0 = (const float*)d_in[13];
  const float* a1 = (const float*)d_in[14];
  const float* a2 = (const float*)d_in[15];
  const float* v0 = (const float*)d_in[16];
  const float* v1 = (const float*)d_in[17];
  const float* v2 = (const float*)d_in[18];
  const float* g1 = (const float*)d_in[19];
  const float* g2 = (const float*)d_in[20];
  const float* k_k = (const float*)d_in[21];
  const float* k_a = (const float*)d_in[22];
  const float* r_k = (const float*)d_in[23];
  const float* Wr = (const float*)d_in[24];
  const float* Wk = (const float*)d_in[25];
  const float* Wv = (const float*)d_in[26];
  const float* Wo = (const float*)d_in[27];
  const float* ln_w = (const float*)d_in[28];
  const float* ln_b = (const float*)d_in[29];

  // ---- ws layout ----
  char* ws = (char*)d_ws;
  u16* WOB  = (u16*)(ws + 0);
  u16* WRB  = (u16*)(ws + 8388608);
  u16* B2W  = (u16*)(ws + 36175872);
  u16* PBUF = (u16*)(ws + 38797312);
  u16* RB   = (u16*)(ws + 44040192);
  u16* KB   = (u16*)(ws + 60817408);
  u16* VB   = (u16*)(ws + 77594624);
  u16* YB   = (u16*)(ws + 94371840);
  float* DEC  = (float*)(ws + 8388608);
  u16* AO   = (u16*)(ws + 8388608);

  // ---- d_out scratch ----
  float* out       = (float*)d_out;
  float* shift_out = out + 8388608;
  float* wkv_out   = out + 8396800;
  float* vf_out    = out + 8921088;
  u16* XRKV = (u16*)d_out;
  u16* WINb = (u16*)d_out;
  u16* AINb = (u16*)((char*)d_out + 16777216);
  u16* VINb = (u16*)((char*)d_out + 35684352);

  // merged weight prep (casts + transposes, one launch)
  k_wprep<<<18944, 256, 0, stream>>>(Wr, Wk, Wv, Wo, w1, a1, v1, g1, w2, a2, v2, g2, (u16*)ws);

  // token-shift mix precompute
  k_prep4<<<8192, 256, 0, stream>>>(x, shift_in, x_r, x_k, x_v, x_w,
                                    XRKV, XRKV + 8388608u, XRKV + 16777216u, XRKV + 25165824u);

  // fused r/k/v + stage-1 GEMM (1D grid, XCD-chunked swizzle, BK=64, pipelined)
  k_gemm_rkv<<<1696, 256, 0, stream>>>(XRKV, x, shift_in, x_a, x_g,
                                       WRB, (float*)PBUF, RB, 2048, 2048, 2048, 2048, 53);

  // fused stage-2 GEMMs
  k_gemm_s2<<<2048, 256, 0, stream>>>(PBUF, nullptr, nullptr, nullptr, nullptr,
                                      B2W, nullptr, (u16*)d_out, 0, 640, 128, 2048, 64);

  // elementwise post
  k_post1<<<32768, 256, 0, stream>>>(KB, VB, WINb, AINb, VINb, v_first,
                                     w0, a0, v0, k_k, k_a, DEC);

  // sequential WKV scan (v6: asm-pinned prefetch, counted vmcnt)
  k_scan<<<1024, 64, 0, stream>>>(RB, DEC, KB, VB, VINb, AINb, wkv_in, YB, wkv_out);

  // groupnorm + bonus + gate
  k_post2<<<32768, 256, 0, stream>>>(YB, RB, KB, VB, (u16*)((char*)d_out + 52461568),
                                     r_k, ln_w, ln_b, AO);

  // final GEMM -> out
  k_gemm_fin<<<512, 256, 0, stream>>>(AO, nullptr, nullptr, nullptr, nullptr,
                                      WOB, out, nullptr, 2048, 2048, 2048, 2048, 16);

  // small outputs last (XV dead; shift_out region safe now)
  k_shift<<<8, 256, 0, stream>>>(x, shift_out);
  hipMemcpyAsync(vf_out, v_first, 33554432, hipMemcpyDeviceToDevice, stream);
}